// Round 10
// baseline (1488.446 us; speedup 1.0000x reference)
//
#include <hip/hip_runtime.h>
#include <math.h>

#define UNITS   128
#define NRBF    10
#define SBF     9
#define NLAYERS 3
#define NELEM   95
#define NTOTAL  60000
#define NLOCAL  50000
#define NGHOST  10000
#define NEDGE   250000
#define NTRIPLE 1000000
#define CUTOFF  5.0f
#define TBCUT   4.0f
#define PI_F    3.14159265358979323846f
#define FSTR    424   // feat row stride in ushorts: 13 kb * 32 + 8 pad

typedef __attribute__((ext_vector_type(8))) short short8;
typedef __attribute__((ext_vector_type(4))) float f32x4;

__device__ __forceinline__ float sigm(float x){ return 1.0f/(1.0f+__expf(-x)); }
__device__ __forceinline__ float silu(float x){ return x/(1.0f+__expf(-x)); }
__device__ __forceinline__ float polycut(float r){
    float q = r*(1.0f/TBCUT);
    float q2 = q*q, q3 = q2*q;
    float p = 1.0f - 6.0f*q2*q3 + 15.0f*q2*q2 - 10.0f*q3;
    return (r <= TBCUT) ? p : 0.0f;
}
__device__ __forceinline__ ushort f2bf(float x){
    unsigned u = __float_as_uint(x);
    unsigned r = (u + 0x7fffu + ((u>>16)&1u)) >> 16;
    return (ushort)r;
}
__device__ __forceinline__ float bf2f(ushort h){
    return __uint_as_float(((unsigned)h) << 16);
}
__device__ __forceinline__ void fma4s(float4& acc, float s, const float4& v){
    acc.x = fmaf(s, v.x, acc.x);
    acc.y = fmaf(s, v.y, acc.y);
    acc.z = fmaf(s, v.z, acc.z);
    acc.w = fmaf(s, v.w, acc.w);
}
__device__ __forceinline__ f32x4 splat4(float x){ f32x4 v = {x,x,x,x}; return v; }
__device__ __forceinline__ float gatef(float xm, float xg){
    float d = (1.0f+__expf(-xm))*(1.0f+__expf(-xg));
    return xm*__builtin_amdgcn_rcpf(d);
}

// ---------------- edge geometry + rbf (original edge order) ----------------
__global__ void k_edge_geom(const float* __restrict__ pos, const float* __restrict__ cell,
                            const float* __restrict__ pbc, const int* __restrict__ src,
                            const int* __restrict__ dst, const int* __restrict__ batch,
                            float* __restrict__ evec, float* __restrict__ elen,
                            float* __restrict__ rbf0){
    int e = blockIdx.x*blockDim.x + threadIdx.x;
    if (e >= NEDGE) return;
    int s = src[e], d = dst[e];
    int b = batch[s];
    const float* C = cell + b*9;
    float p0 = pbc[e*3+0], p1 = pbc[e*3+1], p2 = pbc[e*3+2];
    float vx = pos[s*3+0] - (pos[d*3+0] + p0*C[0] + p1*C[3] + p2*C[6]);
    float vy = pos[s*3+1] - (pos[d*3+1] + p0*C[1] + p1*C[4] + p2*C[7]);
    float vz = pos[s*3+2] - (pos[d*3+2] + p0*C[2] + p1*C[5] + p2*C[8]);
    float r = sqrtf(vx*vx + vy*vy + vz*vz);
    evec[e*3+0] = vx; evec[e*3+1] = vy; evec[e*3+2] = vz;
    elen[e] = r;
    #pragma unroll
    for (int i = 0; i < NRBF; i++){
        float mu = (CUTOFF/(NRBF-1))*i;
        float dm = r - mu;
        rbf0[e*NRBF + i] = __expf(-dm*dm*2.0f);
    }
}

// ---------------- counting sort of edges by src ----------------
__global__ void k_hist(const int* __restrict__ esrc, int* __restrict__ hist){
    int e = blockIdx.x*blockDim.x + threadIdx.x;
    if (e >= NEDGE) return;
    atomicAdd(&hist[esrc[e]], 1);
}
__global__ void k_scan(const int* __restrict__ hist, int* __restrict__ offs){
    __shared__ int part[256];
    int tid = threadIdx.x;
    const int chunk = (NLOCAL + 255)/256;
    int beg = tid*chunk, end = min(beg+chunk, NLOCAL);
    int s = 0;
    for (int i = beg; i < end; i++) s += hist[i];
    part[tid] = s;
    __syncthreads();
    for (int off = 1; off < 256; off <<= 1){
        int v = (tid >= off) ? part[tid-off] : 0;
        __syncthreads();
        part[tid] += v;
        __syncthreads();
    }
    int base = (tid == 0) ? 0 : part[tid-1];
    for (int i = beg; i < end; i++){ offs[i] = base; base += hist[i]; }
}
__global__ void k_scatter(const int* __restrict__ esrc, const int* __restrict__ edst,
                          int* __restrict__ offs, int* __restrict__ perm,
                          int* __restrict__ pinv, int* __restrict__ esrc_s,
                          int* __restrict__ edst_s){
    int e = blockIdx.x*blockDim.x + threadIdx.x;
    if (e >= NEDGE) return;
    int s = esrc[e];
    int pos = atomicAdd(&offs[s], 1);
    perm[pos] = e;
    pinv[e] = pos;
    esrc_s[pos] = s;
    edst_s[pos] = edst[e];
}

// ---------------- atom embedding gather (f32 + bf16 mirror) ----------------
__global__ void k_embed(const int* __restrict__ anum, const float* __restrict__ embw,
                        float* __restrict__ A, ushort* __restrict__ Ah){
    int t = blockIdx.x*blockDim.x + threadIdx.x;
    if (t >= NTOTAL*32) return;
    int a = t >> 5, q = t & 31;
    float4 v = ((const float4*)embw)[anum[a]*32 + q];
    ((float4*)A)[t] = v;
    ushort4 h;
    h.x = f2bf(v.x); h.y = f2bf(v.y); h.z = f2bf(v.z); h.w = f2bf(v.w);
    ((ushort4*)Ah)[t] = h;
}

// ---------------- edge encoding -> Eh at SORTED position ----------------
__global__ void k_edge_enc(const float* __restrict__ rbf0, const float* __restrict__ encw,
                           const float* __restrict__ encb, const int* __restrict__ pinv,
                           ushort* __restrict__ Eh){
    int t = blockIdx.x*blockDim.x + threadIdx.x;
    if (t >= NEDGE*32) return;
    int e = t >> 5, q = t & 31;
    float4 acc = ((const float4*)encb)[q];
    const float4* W4 = (const float4*)encw;
    #pragma unroll
    for (int r = 0; r < NRBF; r++){
        float rv = rbf0[e*NRBF + r];
        fma4s(acc, rv, W4[r*32 + q]);
    }
    ushort4 h;
    h.x = f2bf(acc.x); h.y = f2bf(acc.y); h.z = f2bf(acc.z); h.w = f2bf(acc.w);
    ((ushort4*)(Eh + (size_t)pinv[e]*UNITS))[q] = h;
}

// ---------------- pack main gated-MLP weights: [L][mat:4][kb:12][nt:8][lane:64][j:8] ----------------
__global__ void k_pack_w(const float* __restrict__ gewm, const float* __restrict__ gewg,
                         const float* __restrict__ gawm, const float* __restrict__ gawg,
                         ushort* __restrict__ wp){
    int t = blockIdx.x*blockDim.x + threadIdx.x;
    if (t >= 3*4*12*8*64) return;
    int lane = t & 63;
    int nt   = (t>>6) & 7;
    int rest = t >> 9;
    int kb   = rest % 12;
    int r2   = rest / 12;
    int mat  = r2 & 3;
    int L    = r2 >> 2;
    const float* src;
    if      (mat == 0) src = gewm;
    else if (mat == 1) src = gewg;
    else if (mat == 2) src = gawm;
    else               src = gawg;
    src += (size_t)L*384*128;
    int n = nt*16 + (lane & 15);
    int kbase = kb*32 + (lane>>4)*8;
    ushort* dst = wp + (size_t)t*8;
    #pragma unroll
    for (int j = 0; j < 8; j++) dst[j] = f2bf(src[(size_t)(kbase+j)*128 + n]);
}

// ---------------- pack kb12 ext weights: (tbgw @ W_E) rows at aux k=10..18 ----------------
__global__ void k_pack_ext(const float* __restrict__ gewm, const float* __restrict__ gewg,
                           const float* __restrict__ tbg, ushort* __restrict__ wext){
    int t = blockIdx.x*blockDim.x + threadIdx.x;
    if (t >= 3*2*512) return;
    int lane = t & 63;
    int nt   = (t>>6) & 7;
    int mat  = (t>>9) & 1;
    int L    = t >> 10;
    const float* W = ((mat==0)? gewm : gewg) + (size_t)L*384*128;
    const float* tg = tbg + (size_t)L*SBF*UNITS;
    int n = nt*16 + (lane & 15);
    ushort* dst = wext + (size_t)t*8;
    #pragma unroll
    for (int j = 0; j < 8; j++){
        int k = (lane>>4)*8 + j;
        float v = 0.0f;
        if (k >= 10 && k <= 18){
            int s = k - 10;
            for (int kk = 0; kk < 128; kk++)
                v = fmaf(tg[s*UNITS+kk], W[(size_t)(256+kk)*128 + n], v);
        }
        dst[j] = f2bf(v);
    }
}

// ---------------- pack aux B mats: el_e, el_a, tbgate ----------------
__global__ void k_pack_aux(const float* __restrict__ elew, const float* __restrict__ elaw,
                           const float* __restrict__ tbg, ushort* __restrict__ waux){
    int t = blockIdx.x*blockDim.x + threadIdx.x;
    if (t >= 3*3*512) return;
    int lane = t & 63;
    int nt   = (t>>6) & 7;
    int rest = t >> 9;
    int mat  = rest % 3;
    int L    = rest / 3;
    int n = nt*16 + (lane & 15);
    ushort* dst = waux + (size_t)t*8;
    #pragma unroll
    for (int j = 0; j < 8; j++){
        int k = (lane>>4)*8 + j;
        float v = 0.0f;
        if (mat == 0){ if (k < 10) v = elew[(size_t)L*NRBF*UNITS + k*UNITS + n]; }
        else if (mat == 1){ if (k < 10) v = elaw[(size_t)L*NRBF*UNITS + k*UNITS + n]; }
        else { if (k >= 10 && k <= 18) v = tbg[(size_t)L*SBF*UNITS + (k-10)*UNITS + n]; }
        dst[j] = f2bf(v);
    }
}

// ---------------- bias totals: btot[L][mat:2][128] = be + tbb @ W_E ----------------
__global__ void k_pack_bias(const float* __restrict__ gewm, const float* __restrict__ gewg,
                            const float* __restrict__ gebm, const float* __restrict__ gebg,
                            const float* __restrict__ tbb, float* __restrict__ btot){
    int t = blockIdx.x*blockDim.x + threadIdx.x;
    if (t >= 3*2*128) return;
    int n = t & 127;
    int mat = (t>>7) & 1;
    int L = t >> 8;
    const float* W = ((mat==0)? gewm : gewg) + (size_t)L*384*128;
    const float* be = ((mat==0)? gebm : gebg) + (size_t)L*UNITS;
    const float* tb = tbb + (size_t)L*UNITS;
    float v = be[n];
    for (int kk = 0; kk < 128; kk++)
        v = fmaf(tb[kk], W[(size_t)(256+kk)*128 + n], v);
    btot[t] = v;
}

// ---------------- per-layer: atom sbf mlp (COPY=1: also agg <- atomA; COPY=0: read agg) ----------------
template<int COPY>
__global__ void k_tb_mlp(const float* __restrict__ A, const float* __restrict__ W,
                         const float* __restrict__ b, float* __restrict__ out,
                         float* __restrict__ agg){
    int a = blockIdx.x*blockDim.x + threadIdx.x;
    if (a >= NLOCAL) return;
    float acc[SBF];
    #pragma unroll
    for (int s = 0; s < SBF; s++) acc[s] = b[s];
    const float4* row4 = COPY ? (const float4*)(A + (size_t)a*UNITS)
                              : (const float4*)(agg + (size_t)a*UNITS);
    float4* agg4 = (float4*)(agg + (size_t)a*UNITS);
    for (int k4 = 0; k4 < 32; k4++){
        float4 v = row4[k4];
        if (COPY) agg4[k4] = v;
        const float* w = W + (k4*4)*SBF;
        #pragma unroll
        for (int s = 0; s < SBF; s++){
            acc[s] = fmaf(v.x, w[s],        acc[s]);
            acc[s] = fmaf(v.y, w[s+SBF],    acc[s]);
            acc[s] = fmaf(v.z, w[s+2*SBF],  acc[s]);
            acc[s] = fmaf(v.w, w[s+3*SBF],  acc[s]);
        }
    }
    #pragma unroll
    for (int s = 0; s < SBF; s++) out[a*SBF + s] = sigm(acc[s]);
}

// ---------------- one-time triple compaction (stores SORTED ij position) ----------------
__global__ void k_triple_compact(const float* __restrict__ evec, const float* __restrict__ elen,
                                 const int* __restrict__ esrc, const int* __restrict__ tbi,
                                 const int* __restrict__ pinv,
                                 int* __restrict__ cnt, int* __restrict__ c_ij,
                                 int* __restrict__ c_ka, float* __restrict__ c_cf){
    int t = blockIdx.x*blockDim.x + threadIdx.x;
    if (t >= NTRIPLE) return;
    int ij = tbi[2*t], ik = tbi[2*t+1];
    float rij = elen[ij], rik = elen[ik];
    float cc = polycut(rij)*polycut(rik);
    if (cc == 0.0f) return;
    float ax = evec[ij*3+0], ay = evec[ij*3+1], az = evec[ij*3+2];
    float bx = evec[ik*3+0], by = evec[ik*3+1], bz = evec[ik*3+2];
    float dot = ax*bx + ay*by + az*bz;
    float c = dot/(rij*rik + 1e-12f);
    c = fminf(fmaxf(c, -1.0f + 1e-7f), 1.0f - 1e-7f);
    float a0 = 1.0f, a1 = c, a2 = 2.0f*c*c - 1.0f;
    float x = rik*(PI_F/TBCUT);
    float s1, c1;
    sincosf(x, &s1, &c1);
    float s2 = 2.0f*s1*c1;
    float s3 = s1*(3.0f - 4.0f*s1*s1);
    float inv = 1.0f/(rik + 1e-6f);
    float r0 = s1*inv, r1 = s2*inv, r2 = s3*inv;
    int idx = atomicAdd(cnt, 1);
    c_ij[idx] = pinv[ij];
    c_ka[idx] = esrc[ik];
    c_cf[idx + 0*NTRIPLE] = r0*a0*cc;
    c_cf[idx + 1*NTRIPLE] = r0*a1*cc;
    c_cf[idx + 2*NTRIPLE] = r0*a2*cc;
    c_cf[idx + 3*NTRIPLE] = r1*a0*cc;
    c_cf[idx + 4*NTRIPLE] = r1*a1*cc;
    c_cf[idx + 5*NTRIPLE] = r1*a2*cc;
    c_cf[idx + 6*NTRIPLE] = r2*a0*cc;
    c_cf[idx + 7*NTRIPLE] = r2*a1*cc;
    c_cf[idx + 8*NTRIPLE] = r2*a2*cc;
}

// ---------------- per-layer: apply compacted triples (grid-stride) ----------------
__global__ void k_triple_apply(const int* __restrict__ cnt, const int* __restrict__ c_ij,
                               const int* __restrict__ c_ka, const float* __restrict__ c_cf,
                               const float* __restrict__ amlp, float* __restrict__ tb_out){
    int n = *cnt;
    for (int t = blockIdx.x*blockDim.x + threadIdx.x; t < n; t += gridDim.x*blockDim.x){
        int ij = c_ij[t], ka = c_ka[t];
        const float* am = amlp + (size_t)ka*SBF;
        float* dst = tb_out + (size_t)ij*SBF;
        #pragma unroll
        for (int s = 0; s < SBF; s++)
            atomicAdd(dst+s, c_cf[t + s*NTRIPLE]*am[s]);
    }
}

// ---------------- fused per-layer gated blocks (ge + ga), all-MFMA, SORTED edges ----------------
// Edges sorted by src: block's 32 edges have ~6-7 distinct src atoms -> Ah[src] L1 hits,
// epilogue-2 does LDS segmented reduction over src runs (few atomics, no same-addr serialization).
// Eh / tb_out stored in sorted space; rbf0 read via perm indirection.
__global__
void k_gated_fused(const ushort* __restrict__ Ah, ushort* __restrict__ Eh,
                   const int* __restrict__ esrc_s, const int* __restrict__ edst_s,
                   const int* __restrict__ perm,
                   const float* __restrict__ rbf0, const float* __restrict__ tb_out,
                   const ushort* __restrict__ Wem, const ushort* __restrict__ Weg,
                   const ushort* __restrict__ Wam, const ushort* __restrict__ Wag,
                   const ushort* __restrict__ WxM, const ushort* __restrict__ WxG,
                   const ushort* __restrict__ Ble, const ushort* __restrict__ Bla,
                   const ushort* __restrict__ Bte,
                   const float* __restrict__ btm, const float* __restrict__ btg,
                   const float* __restrict__ bam, const float* __restrict__ bag,
                   const float* __restrict__ tbb, const float* __restrict__ eleb,
                   const float* __restrict__ elab,
                   float* __restrict__ agg){
    __shared__ __align__(16) ushort feat_s[32*FSTR];
    __shared__ int src_s[32];
    __shared__ int dst_s[32];
    __shared__ int perm_s[32];

    const int tid = threadIdx.x;
    const int e0  = blockIdx.x*32;

    if (tid < 32){
        int e = min(e0 + tid, NEDGE-1);
        src_s[tid]  = esrc_s[e];
        dst_s[tid]  = edst_s[e];
        perm_s[tid] = perm[e];
    }
    __syncthreads();

    // main staging: 32 rows x 48 short8, pure bf16 copies, 6/thread
    #pragma unroll
    for (int j = 0; j < 6; j++){
        int idx = j*256 + tid;
        int m   = idx/48;
        int k8  = idx - m*48;
        const ushort* p;
        if (k8 < 16)      p = Ah + (size_t)src_s[m]*UNITS + k8*8;
        else if (k8 < 32) p = Ah + (size_t)dst_s[m]*UNITS + (k8-16)*8;
        else {
            int e = min(e0 + m, NEDGE-1);
            p = Eh + (size_t)e*UNITS + (k8-32)*8;
        }
        *(short8*)&feat_s[m*FSTR + k8*8] = *(const short8*)p;
    }
    // aux staging: 32 rows x 4 short8 = [rbf(orig order via perm) | tb9(sorted) | 0]
    if (tid < 128){
        int m = tid >> 2, j8 = tid & 3;
        int e  = min(e0 + m, NEDGE-1);
        int pe = perm_s[m];
        short8 h;
        #pragma unroll
        for (int jj = 0; jj < 8; jj++){
            int k = j8*8 + jj;
            float x = 0.0f;
            if (k < 10)      x = rbf0[(size_t)pe*NRBF + k];
            else if (k < 19) x = tb_out[(size_t)e*SBF + (k-10)];
            h[jj] = (short)f2bf(x);
        }
        *(short8*)&feat_s[m*FSTR + 384 + j8*8] = h;
    }
    __syncthreads();

    const int lane = tid & 63;
    const int w    = tid >> 6;
    const int quad = lane >> 4;
    const int l15  = lane & 15;

    float btm_c[2], btg_c[2], bam_c[2], bag_c[2], tbb_c[2], leb_c[2];
    #pragma unroll
    for (int ct = 0; ct < 2; ct++){
        int c = w*32 + ct*16 + l15;
        btm_c[ct] = btm[c]; btg_c[ct] = btg[c];
        bam_c[ct] = bam[c]; bag_c[ct] = bag[c];
        tbb_c[ct] = tbb[c]; leb_c[ct] = eleb[c];
    }

    f32x4 acc_em[2][2], acc_eg[2][2], acc_am[2][2], acc_ag[2][2], acc_te[2][2], acc_le[2][2];
    #pragma unroll
    for (int mt = 0; mt < 2; mt++)
        #pragma unroll
        for (int ct = 0; ct < 2; ct++){
            acc_em[mt][ct] = splat4(btm_c[ct]); acc_eg[mt][ct] = splat4(btg_c[ct]);
            acc_am[mt][ct] = splat4(bam_c[ct]); acc_ag[mt][ct] = splat4(bag_c[ct]);
            acc_te[mt][ct] = splat4(tbb_c[ct]); acc_le[mt][ct] = splat4(leb_c[ct]);
        }

    const ushort* a0p = feat_s + l15*FSTR + quad*8;
    const ushort* a1p = a0p + 16*FSTR;

    // Phase 1: ge kb0..11; ga kb0..7
    for (int ks = 0; ks < 12; ks++){
        short8 a0 = *(const short8*)(a0p + ks*32);
        short8 a1 = *(const short8*)(a1p + ks*32);
        #pragma unroll
        for (int ct = 0; ct < 2; ct++){
            int nt = w*2 + ct;
            size_t boff = ((size_t)(ks*8 + nt)*64 + lane)*8;
            short8 b_em = *(const short8*)(Wem + boff);
            short8 b_eg = *(const short8*)(Weg + boff);
            acc_em[0][ct] = __builtin_amdgcn_mfma_f32_16x16x32_bf16(a0, b_em, acc_em[0][ct], 0, 0, 0);
            acc_em[1][ct] = __builtin_amdgcn_mfma_f32_16x16x32_bf16(a1, b_em, acc_em[1][ct], 0, 0, 0);
            acc_eg[0][ct] = __builtin_amdgcn_mfma_f32_16x16x32_bf16(a0, b_eg, acc_eg[0][ct], 0, 0, 0);
            acc_eg[1][ct] = __builtin_amdgcn_mfma_f32_16x16x32_bf16(a1, b_eg, acc_eg[1][ct], 0, 0, 0);
            if (ks < 8){
                short8 b_am = *(const short8*)(Wam + boff);
                short8 b_ag = *(const short8*)(Wag + boff);
                acc_am[0][ct] = __builtin_amdgcn_mfma_f32_16x16x32_bf16(a0, b_am, acc_am[0][ct], 0, 0, 0);
                acc_am[1][ct] = __builtin_amdgcn_mfma_f32_16x16x32_bf16(a1, b_am, acc_am[1][ct], 0, 0, 0);
                acc_ag[0][ct] = __builtin_amdgcn_mfma_f32_16x16x32_bf16(a0, b_ag, acc_ag[0][ct], 0, 0, 0);
                acc_ag[1][ct] = __builtin_amdgcn_mfma_f32_16x16x32_bf16(a1, b_ag, acc_ag[1][ct], 0, 0, 0);
            }
        }
    }
    // kb12 (aux fragment): ge ext + te + le
    short8 a0x = *(const short8*)(a0p + 384);
    short8 a1x = *(const short8*)(a1p + 384);
    #pragma unroll
    for (int ct = 0; ct < 2; ct++){
        size_t bx = ((size_t)(w*2 + ct)*64 + lane)*8;
        short8 b_xm = *(const short8*)(WxM + bx);
        short8 b_xg = *(const short8*)(WxG + bx);
        short8 b_te = *(const short8*)(Bte + bx);
        short8 b_le = *(const short8*)(Ble + bx);
        acc_em[0][ct] = __builtin_amdgcn_mfma_f32_16x16x32_bf16(a0x, b_xm, acc_em[0][ct], 0, 0, 0);
        acc_em[1][ct] = __builtin_amdgcn_mfma_f32_16x16x32_bf16(a1x, b_xm, acc_em[1][ct], 0, 0, 0);
        acc_eg[0][ct] = __builtin_amdgcn_mfma_f32_16x16x32_bf16(a0x, b_xg, acc_eg[0][ct], 0, 0, 0);
        acc_eg[1][ct] = __builtin_amdgcn_mfma_f32_16x16x32_bf16(a1x, b_xg, acc_eg[1][ct], 0, 0, 0);
        acc_te[0][ct] = __builtin_amdgcn_mfma_f32_16x16x32_bf16(a0x, b_te, acc_te[0][ct], 0, 0, 0);
        acc_te[1][ct] = __builtin_amdgcn_mfma_f32_16x16x32_bf16(a1x, b_te, acc_te[1][ct], 0, 0, 0);
        acc_le[0][ct] = __builtin_amdgcn_mfma_f32_16x16x32_bf16(a0x, b_le, acc_le[0][ct], 0, 0, 0);
        acc_le[1][ct] = __builtin_amdgcn_mfma_f32_16x16x32_bf16(a1x, b_le, acc_le[1][ct], 0, 0, 0);
    }

    // Epilogue 1: E_new = E_old + tbgate + gate*el_e
    __syncthreads();
    #pragma unroll
    for (int mt = 0; mt < 2; mt++){
        #pragma unroll
        for (int r = 0; r < 4; r++){
            int ml = mt*16 + quad*4 + r;
            int e  = e0 + ml;
            if (e >= NEDGE) continue;
            #pragma unroll
            for (int ct = 0; ct < 2; ct++){
                int c = w*32 + ct*16 + l15;
                float gate = gatef(acc_em[mt][ct][r], acc_eg[mt][ct][r]);
                float enew = bf2f(feat_s[ml*FSTR + 256 + c])
                           + acc_te[mt][ct][r] + gate*acc_le[mt][ct][r];
                ushort hb = f2bf(enew);
                feat_s[ml*FSTR + 256 + c] = hb;
                Eh[(size_t)e*UNITS + c] = hb;
            }
        }
    }
    __syncthreads();

    // Phase 2: ga kb8..11 on E_new + la
    for (int ks = 8; ks < 12; ks++){
        short8 a0 = *(const short8*)(a0p + ks*32);
        short8 a1 = *(const short8*)(a1p + ks*32);
        #pragma unroll
        for (int ct = 0; ct < 2; ct++){
            int nt = w*2 + ct;
            size_t boff = ((size_t)(ks*8 + nt)*64 + lane)*8;
            short8 b_am = *(const short8*)(Wam + boff);
            short8 b_ag = *(const short8*)(Wag + boff);
            acc_am[0][ct] = __builtin_amdgcn_mfma_f32_16x16x32_bf16(a0, b_am, acc_am[0][ct], 0, 0, 0);
            acc_am[1][ct] = __builtin_amdgcn_mfma_f32_16x16x32_bf16(a1, b_am, acc_am[1][ct], 0, 0, 0);
            acc_ag[0][ct] = __builtin_amdgcn_mfma_f32_16x16x32_bf16(a0, b_ag, acc_ag[0][ct], 0, 0, 0);
            acc_ag[1][ct] = __builtin_amdgcn_mfma_f32_16x16x32_bf16(a1, b_ag, acc_ag[1][ct], 0, 0, 0);
        }
    }
    f32x4 acc_la[2][2];
    {
        #pragma unroll
        for (int ct = 0; ct < 2; ct++){
            float lb = elab[w*32 + ct*16 + l15];
            acc_la[0][ct] = splat4(lb);
            acc_la[1][ct] = splat4(lb);
            size_t bx = ((size_t)(w*2 + ct)*64 + lane)*8;
            short8 b_la = *(const short8*)(Bla + bx);
            acc_la[0][ct] = __builtin_amdgcn_mfma_f32_16x16x32_bf16(a0x, b_la, acc_la[0][ct], 0, 0, 0);
            acc_la[1][ct] = __builtin_amdgcn_mfma_f32_16x16x32_bf16(a1x, b_la, acc_la[1][ct], 0, 0, 0);
        }
    }

    // Epilogue 2: LDS segmented reduction over src runs, then few atomics
    __syncthreads();                       // all waves done reading feat_s
    float* red = (float*)feat_s;           // 32*128 f32 = 16 KB (fits in feat_s)
    #pragma unroll
    for (int mt = 0; mt < 2; mt++){
        #pragma unroll
        for (int r = 0; r < 4; r++){
            int ml = mt*16 + quad*4 + r;
            int e  = e0 + ml;
            #pragma unroll
            for (int ct = 0; ct < 2; ct++){
                int c = w*32 + ct*16 + l15;
                float v = 0.0f;
                if (e < NEDGE){
                    float gate = gatef(acc_am[mt][ct][r], acc_ag[mt][ct][r]);
                    v = gate*acc_la[mt][ct][r];
                }
                red[ml*UNITS + c] = v;
            }
        }
    }
    __syncthreads();
    {
        int c  = tid & 127;
        int rw = (tid >> 7)*16;
        float acc = red[rw*UNITS + c];
        int cur = src_s[rw];
        #pragma unroll
        for (int r = rw+1; r < rw+16; r++){
            int s = src_s[r];
            float v = red[r*UNITS + c];
            if (s != cur){
                atomicAdd(&agg[(size_t)cur*UNITS + c], acc);
                cur = s; acc = v;
            } else acc += v;
        }
        atomicAdd(&agg[(size_t)cur*UNITS + c], acc);
    }
}

// ---------------- ghost expansion: bf16 mirror only (agg IS the f32 features) ----------------
__global__ void k_expand(const float* __restrict__ agg, const int* __restrict__ gmap,
                         ushort* __restrict__ Ah){
    int t = blockIdx.x*blockDim.x + threadIdx.x;
    if (t >= NTOTAL*32) return;
    int i = t >> 5, q = t & 31;
    int row = (i < NLOCAL) ? i : gmap[i - NLOCAL];
    float4 v = ((const float4*)agg)[(size_t)row*32 + q];
    ushort4 h;
    h.x = f2bf(v.x); h.y = f2bf(v.y); h.z = f2bf(v.z); h.w = f2bf(v.w);
    ((ushort4*)Ah)[t] = h;
}

// ---------------- final readout + global sum ----------------
__global__ void k_final(const float* __restrict__ A, const float* __restrict__ W1,
                        const float* __restrict__ b1, const float* __restrict__ W2,
                        const float* __restrict__ b2, const int* __restrict__ anum,
                        const float* __restrict__ escl, const float* __restrict__ eshf,
                        float* __restrict__ out){
    __shared__ float red[256];
    const int tid  = threadIdx.x;
    const int c    = tid & 127;
    const int half = tid >> 7;
    float b1c = b1[c];
    float w2c = W2[c];
    float b2v = b2[0];
    float tpart = 0.0f;
    const int npairs = NLOCAL/2;
    for (int p = blockIdx.x; p < npairs; p += gridDim.x){
        int a = 2*p + half;
        const float* h = A + (size_t)a*UNITS;
        float acc = b1c;
        for (int k = 0; k < UNITS; k++)
            acc = fmaf(h[k], W1[k*UNITS + c], acc);
        float hid = silu(acc);
        int z = anum[a];
        float sc = escl[z];
        tpart = fmaf(sc*hid, w2c, tpart);
        if (c == 0) tpart += sc*b2v + eshf[z];
    }
    red[tid] = tpart;
    __syncthreads();
    for (int s = 128; s > 0; s >>= 1){
        if (tid < s) red[tid] += red[tid + s];
        __syncthreads();
    }
    if (tid == 0) atomicAdd(out, red[0]);
}

extern "C" void kernel_launch(void* const* d_in, const int* in_sizes, int n_in,
                              void* d_out, int out_size, void* d_ws, size_t ws_size,
                              hipStream_t stream){
    const int*   anum  = (const int*)d_in[0];
    const float* pos   = (const float*)d_in[1];
    const float* cell  = (const float*)d_in[2];
    const float* pbc   = (const float*)d_in[3];
    const int*   esrc  = (const int*)d_in[4];
    const int*   edst  = (const int*)d_in[5];
    const int*   tbi   = (const int*)d_in[6];
    const int*   batch = (const int*)d_in[7];
    const int*   gmap  = (const int*)d_in[8];
    const float* embw  = (const float*)d_in[10];
    const float* encw  = (const float*)d_in[11];
    const float* encb  = (const float*)d_in[12];
    const float* tbaw  = (const float*)d_in[13];
    const float* tbab  = (const float*)d_in[14];
    const float* tbgw  = (const float*)d_in[15];
    const float* tbgb  = (const float*)d_in[16];
    const float* gewm  = (const float*)d_in[17];
    const float* gebm  = (const float*)d_in[18];
    const float* gewg  = (const float*)d_in[19];
    const float* gebg  = (const float*)d_in[20];
    const float* elew  = (const float*)d_in[21];
    const float* eleb  = (const float*)d_in[22];
    const float* gawm  = (const float*)d_in[23];
    const float* gabm  = (const float*)d_in[24];
    const float* gawg  = (const float*)d_in[25];
    const float* gabg  = (const float*)d_in[26];
    const float* elaw  = (const float*)d_in[27];
    const float* elab  = (const float*)d_in[28];
    const float* fw1   = (const float*)d_in[29];
    const float* fb1   = (const float*)d_in[30];
    const float* fw2   = (const float*)d_in[31];
    const float* fb2   = (const float*)d_in[32];
    const float* escl  = (const float*)d_in[33];
    const float* eshf  = (const float*)d_in[34];
    (void)in_sizes; (void)n_in; (void)out_size; (void)ws_size;

    float* ws    = (float*)d_ws;
    float* atomA = ws;                                   // NTOTAL*128 f32 (L0 only)
    float* agg   = atomA + (size_t)NTOTAL*UNITS;         // NLOCAL*128 f32
    float* evec  = agg   + (size_t)NLOCAL*UNITS;         // NEDGE*3
    float* elen  = evec  + (size_t)NEDGE*3;              // NEDGE
    float* rbf0  = elen  + (size_t)NEDGE;                // NEDGE*10 (orig order)
    float* tbout = rbf0  + (size_t)NEDGE*NRBF;           // NEDGE*9 (sorted order)
    float* amlp  = tbout + (size_t)NEDGE*SBF;            // NLOCAL*9
    float* btot  = amlp  + (size_t)NLOCAL*SBF;           // 3*2*128
    int*   tcnt  = (int*)(btot + 3*2*128);               // 1 (+3 pad)
    int*   c_ij  = tcnt + 4;                             // NTRIPLE
    int*   c_ka  = c_ij + NTRIPLE;                       // NTRIPLE
    float* c_cf  = (float*)(c_ka + NTRIPLE);             // 9*NTRIPLE
    int*   hist  = (int*)(c_cf + (size_t)9*NTRIPLE);     // NLOCAL
    int*   offs  = hist + NLOCAL;                        // NLOCAL
    int*   perm  = offs + NLOCAL;                        // NEDGE
    int*   pinv  = perm + NEDGE;                         // NEDGE
    int*   esrcs = pinv + NEDGE;                         // NEDGE
    int*   edsts = esrcs + NEDGE;                        // NEDGE
    ushort* edgeEh = (ushort*)(edsts + NEDGE);              // NEDGE*128 bf16 (sorted)
    ushort* atomAh = edgeEh + (size_t)NEDGE*UNITS;          // NTOTAL*128 bf16
    ushort* wmain  = atomAh + (size_t)NTOTAL*UNITS;         // 3*4*49152
    ushort* wext   = wmain + (size_t)3*4*49152;             // 3*2*4096
    ushort* waux   = wext  + (size_t)3*2*4096;              // 3*3*4096

    float* out = (float*)d_out;
    hipMemsetAsync(out, 0, sizeof(float), stream);
    hipMemsetAsync(tcnt, 0, sizeof(int), stream);
    hipMemsetAsync(hist, 0, NLOCAL*sizeof(int), stream);

    k_pack_w   <<<(3*4*12*8*64 + 255)/256, 256, 0, stream>>>(gewm, gewg, gawm, gawg, wmain);
    k_pack_ext <<<(3*2*512 + 255)/256, 256, 0, stream>>>(gewm, gewg, tbgw, wext);
    k_pack_aux <<<(3*3*512 + 255)/256, 256, 0, stream>>>(elew, elaw, tbgw, waux);
    k_pack_bias<<<(3*2*128 + 255)/256, 256, 0, stream>>>(gewm, gewg, gebm, gebg, tbgb, btot);
    k_edge_geom<<<(NEDGE+255)/256, 256, 0, stream>>>(pos, cell, pbc, esrc, edst, batch,
                                                     evec, elen, rbf0);
    // edge sort by src (one-time, layer-independent)
    k_hist   <<<(NEDGE+255)/256, 256, 0, stream>>>(esrc, hist);
    k_scan   <<<1, 256, 0, stream>>>(hist, offs);
    k_scatter<<<(NEDGE+255)/256, 256, 0, stream>>>(esrc, edst, offs, perm, pinv, esrcs, edsts);
    k_embed<<<(NTOTAL*32+255)/256, 256, 0, stream>>>(anum, embw, atomA, atomAh);
    k_edge_enc<<<(NEDGE*32+255)/256, 256, 0, stream>>>(rbf0, encw, encb, pinv, edgeEh);
    k_triple_compact<<<(NTRIPLE+255)/256, 256, 0, stream>>>(evec, elen, esrc, tbi, pinv,
                                                            tcnt, c_ij, c_ka, c_cf);

    const int gemm_blocks = (NEDGE+31)/32;
    for (int L = 0; L < NLAYERS; L++){
        const ushort* wmL = wmain + (size_t)L*4*49152;
        const ushort* wxL = wext  + (size_t)L*2*4096;
        const ushort* waL = waux  + (size_t)L*3*4096;
        if (L == 0)
            k_tb_mlp<1><<<(NLOCAL+255)/256, 256, 0, stream>>>(atomA,
                tbaw + (size_t)L*UNITS*SBF, tbab + (size_t)L*SBF, amlp, agg);
        else
            k_tb_mlp<0><<<(NLOCAL+255)/256, 256, 0, stream>>>(nullptr,
                tbaw + (size_t)L*UNITS*SBF, tbab + (size_t)L*SBF, amlp, agg);
        hipMemsetAsync(tbout, 0, (size_t)NEDGE*SBF*sizeof(float), stream);
        k_triple_apply<<<512, 256, 0, stream>>>(tcnt, c_ij, c_ka, c_cf, amlp, tbout);
        k_gated_fused<<<gemm_blocks, 256, 0, stream>>>(atomAh, edgeEh, esrcs, edsts, perm,
            rbf0, tbout,
            wmL + 0*49152, wmL + 1*49152, wmL + 2*49152, wmL + 3*49152,
            wxL + 0*4096,  wxL + 1*4096,
            waL + 0*4096,  waL + 1*4096, waL + 2*4096,
            btot + (size_t)L*2*128, btot + (size_t)L*2*128 + 128,
            gabm + (size_t)L*UNITS, gabg + (size_t)L*UNITS,
            tbgb + (size_t)L*UNITS, eleb + (size_t)L*UNITS, elab + (size_t)L*UNITS,
            agg);
        if (L < NLAYERS-1)
            k_expand<<<(NTOTAL*32+255)/256, 256, 0, stream>>>(agg, gmap, atomAh);
    }
    k_final<<<1024, 256, 0, stream>>>(agg, fw1, fb1, fw2, fb2, anum, escl, eshf, out);
}

// Round 11
// 1341.839 us; speedup vs baseline: 1.1093x; 1.1093x over previous
//
#include <hip/hip_runtime.h>
#include <math.h>

#define UNITS   128
#define NRBF    10
#define SBF     9
#define NLAYERS 3
#define NELEM   95
#define NTOTAL  60000
#define NLOCAL  50000
#define NGHOST  10000
#define NEDGE   250000
#define NTRIPLE 1000000
#define CUTOFF  5.0f
#define TBCUT   4.0f
#define PI_F    3.14159265358979323846f
#define FSTR    424   // feat row stride in ushorts: 13 kb * 32 + 8 pad

typedef __attribute__((ext_vector_type(8))) short short8;
typedef __attribute__((ext_vector_type(4))) float f32x4;

__device__ __forceinline__ float sigm(float x){ return 1.0f/(1.0f+__expf(-x)); }
__device__ __forceinline__ float silu(float x){ return x/(1.0f+__expf(-x)); }
__device__ __forceinline__ float polycut(float r){
    float q = r*(1.0f/TBCUT);
    float q2 = q*q, q3 = q2*q;
    float p = 1.0f - 6.0f*q2*q3 + 15.0f*q2*q2 - 10.0f*q3;
    return (r <= TBCUT) ? p : 0.0f;
}
__device__ __forceinline__ ushort f2bf(float x){
    unsigned u = __float_as_uint(x);
    unsigned r = (u + 0x7fffu + ((u>>16)&1u)) >> 16;
    return (ushort)r;
}
__device__ __forceinline__ float bf2f(ushort h){
    return __uint_as_float(((unsigned)h) << 16);
}
__device__ __forceinline__ void fma4s(float4& acc, float s, const float4& v){
    acc.x = fmaf(s, v.x, acc.x);
    acc.y = fmaf(s, v.y, acc.y);
    acc.z = fmaf(s, v.z, acc.z);
    acc.w = fmaf(s, v.w, acc.w);
}
__device__ __forceinline__ f32x4 splat4(float x){ f32x4 v = {x,x,x,x}; return v; }
__device__ __forceinline__ float gatef(float xm, float xg){
    float d = (1.0f+__expf(-xm))*(1.0f+__expf(-xg));
    return xm*__builtin_amdgcn_rcpf(d);
}

// ---------------- edge geometry + rbf ----------------
__global__ void k_edge_geom(const float* __restrict__ pos, const float* __restrict__ cell,
                            const float* __restrict__ pbc, const int* __restrict__ src,
                            const int* __restrict__ dst, const int* __restrict__ batch,
                            float* __restrict__ evec, float* __restrict__ elen,
                            float* __restrict__ rbf0){
    int e = blockIdx.x*blockDim.x + threadIdx.x;
    if (e >= NEDGE) return;
    int s = src[e], d = dst[e];
    int b = batch[s];
    const float* C = cell + b*9;
    float p0 = pbc[e*3+0], p1 = pbc[e*3+1], p2 = pbc[e*3+2];
    float vx = pos[s*3+0] - (pos[d*3+0] + p0*C[0] + p1*C[3] + p2*C[6]);
    float vy = pos[s*3+1] - (pos[d*3+1] + p0*C[1] + p1*C[4] + p2*C[7]);
    float vz = pos[s*3+2] - (pos[d*3+2] + p0*C[2] + p1*C[5] + p2*C[8]);
    float r = sqrtf(vx*vx + vy*vy + vz*vz);
    evec[e*3+0] = vx; evec[e*3+1] = vy; evec[e*3+2] = vz;
    elen[e] = r;
    #pragma unroll
    for (int i = 0; i < NRBF; i++){
        float mu = (CUTOFF/(NRBF-1))*i;
        float dm = r - mu;
        rbf0[e*NRBF + i] = __expf(-dm*dm*2.0f);
    }
}

// ---------------- atom embedding gather (f32, all NTOTAL atoms) ----------------
__global__ void k_embed(const int* __restrict__ anum, const float* __restrict__ embw,
                        float* __restrict__ A){
    int t = blockIdx.x*blockDim.x + threadIdx.x;
    if (t >= NTOTAL*32) return;
    int a = t >> 5, q = t & 31;
    ((float4*)A)[t] = ((const float4*)embw)[anum[a]*32 + q];
}

// ---------------- edge encoding: Eh = bf16(rbf0 @ Wenc + benc) ----------------
__global__ void k_edge_enc(const float* __restrict__ rbf0, const float* __restrict__ encw,
                           const float* __restrict__ encb, ushort* __restrict__ Eh){
    int t = blockIdx.x*blockDim.x + threadIdx.x;
    if (t >= NEDGE*32) return;
    int e = t >> 5, q = t & 31;
    float4 acc = ((const float4*)encb)[q];
    const float4* W4 = (const float4*)encw;
    #pragma unroll
    for (int r = 0; r < NRBF; r++){
        float rv = rbf0[e*NRBF + r];
        fma4s(acc, rv, W4[r*32 + q]);
    }
    ushort4 h;
    h.x = f2bf(acc.x); h.y = f2bf(acc.y); h.z = f2bf(acc.z); h.w = f2bf(acc.w);
    ((ushort4*)Eh)[t] = h;
}

// ---------------- pack main gated-MLP weights: [L][mat:4][kb:12][nt:8][lane:64][j:8] ----------------
__global__ void k_pack_w(const float* __restrict__ gewm, const float* __restrict__ gewg,
                         const float* __restrict__ gawm, const float* __restrict__ gawg,
                         ushort* __restrict__ wp){
    int t = blockIdx.x*blockDim.x + threadIdx.x;
    if (t >= 3*4*12*8*64) return;
    int lane = t & 63;
    int nt   = (t>>6) & 7;
    int rest = t >> 9;
    int kb   = rest % 12;
    int r2   = rest / 12;
    int mat  = r2 & 3;
    int L    = r2 >> 2;
    const float* src;
    if      (mat == 0) src = gewm;
    else if (mat == 1) src = gewg;
    else if (mat == 2) src = gawm;
    else               src = gawg;
    src += (size_t)L*384*128;
    int n = nt*16 + (lane & 15);
    int kbase = kb*32 + (lane>>4)*8;
    ushort* dst = wp + (size_t)t*8;
    #pragma unroll
    for (int j = 0; j < 8; j++) dst[j] = f2bf(src[(size_t)(kbase+j)*128 + n]);
}

// ---------------- pack kb12 ext weights: (tbgw @ W_E) rows at aux k=10..18 ----------------
__global__ void k_pack_ext(const float* __restrict__ gewm, const float* __restrict__ gewg,
                           const float* __restrict__ tbg, ushort* __restrict__ wext){
    int t = blockIdx.x*blockDim.x + threadIdx.x;
    if (t >= 3*2*512) return;
    int lane = t & 63;
    int nt   = (t>>6) & 7;
    int mat  = (t>>9) & 1;
    int L    = t >> 10;
    const float* W = ((mat==0)? gewm : gewg) + (size_t)L*384*128;
    const float* tg = tbg + (size_t)L*SBF*UNITS;
    int n = nt*16 + (lane & 15);
    ushort* dst = wext + (size_t)t*8;
    #pragma unroll
    for (int j = 0; j < 8; j++){
        int k = (lane>>4)*8 + j;
        float v = 0.0f;
        if (k >= 10 && k <= 18){
            int s = k - 10;
            for (int kk = 0; kk < 128; kk++)
                v = fmaf(tg[s*UNITS+kk], W[(size_t)(256+kk)*128 + n], v);
        }
        dst[j] = f2bf(v);
    }
}

// ---------------- pack aux B mats: el_e, el_a, tbgate ----------------
__global__ void k_pack_aux(const float* __restrict__ elew, const float* __restrict__ elaw,
                           const float* __restrict__ tbg, ushort* __restrict__ waux){
    int t = blockIdx.x*blockDim.x + threadIdx.x;
    if (t >= 3*3*512) return;
    int lane = t & 63;
    int nt   = (t>>6) & 7;
    int rest = t >> 9;
    int mat  = rest % 3;
    int L    = rest / 3;
    int n = nt*16 + (lane & 15);
    ushort* dst = waux + (size_t)t*8;
    #pragma unroll
    for (int j = 0; j < 8; j++){
        int k = (lane>>4)*8 + j;
        float v = 0.0f;
        if (mat == 0){ if (k < 10) v = elew[(size_t)L*NRBF*UNITS + k*UNITS + n]; }
        else if (mat == 1){ if (k < 10) v = elaw[(size_t)L*NRBF*UNITS + k*UNITS + n]; }
        else { if (k >= 10 && k <= 18) v = tbg[(size_t)L*SBF*UNITS + (k-10)*UNITS + n]; }
        dst[j] = f2bf(v);
    }
}

// ---------------- bias totals: btot[L][mat:2][128] = be + tbb @ W_E ----------------
__global__ void k_pack_bias(const float* __restrict__ gewm, const float* __restrict__ gewg,
                            const float* __restrict__ gebm, const float* __restrict__ gebg,
                            const float* __restrict__ tbb, float* __restrict__ btot){
    int t = blockIdx.x*blockDim.x + threadIdx.x;
    if (t >= 3*2*128) return;
    int n = t & 127;
    int mat = (t>>7) & 1;
    int L = t >> 8;
    const float* W = ((mat==0)? gewm : gewg) + (size_t)L*384*128;
    const float* be = ((mat==0)? gebm : gebg) + (size_t)L*UNITS;
    const float* tb = tbb + (size_t)L*UNITS;
    float v = be[n];
    for (int kk = 0; kk < 128; kk++)
        v = fmaf(tb[kk], W[(size_t)(256+kk)*128 + n], v);
    btot[t] = v;
}

// ---------------- per-layer: atom sbf mlp + seed aggOut <- Fin copy ----------------
__global__ void k_tb_mlp(const float* __restrict__ Fin, const float* __restrict__ W,
                         const float* __restrict__ b, float* __restrict__ out,
                         float* __restrict__ aggOut){
    int a = blockIdx.x*blockDim.x + threadIdx.x;
    if (a >= NLOCAL) return;
    float acc[SBF];
    #pragma unroll
    for (int s = 0; s < SBF; s++) acc[s] = b[s];
    const float4* row4 = (const float4*)(Fin + (size_t)a*UNITS);
    float4* agg4 = (float4*)(aggOut + (size_t)a*UNITS);
    for (int k4 = 0; k4 < 32; k4++){
        float4 v = row4[k4];
        agg4[k4] = v;
        const float* w = W + (k4*4)*SBF;
        #pragma unroll
        for (int s = 0; s < SBF; s++){
            acc[s] = fmaf(v.x, w[s],        acc[s]);
            acc[s] = fmaf(v.y, w[s+SBF],    acc[s]);
            acc[s] = fmaf(v.z, w[s+2*SBF],  acc[s]);
            acc[s] = fmaf(v.w, w[s+3*SBF],  acc[s]);
        }
    }
    #pragma unroll
    for (int s = 0; s < SBF; s++) out[a*SBF + s] = sigm(acc[s]);
}

// ---------------- one-time triple compaction: block-aggregated counter ----------------
// Single-address atomicAdd per THREAD serialized ~30k L2 RMWs (R9/R10 hidden ~200us cost);
// now: ballot per wave + LDS scan -> ONE global atomic per 256-thread block.
__global__ void k_triple_compact(const float* __restrict__ evec, const float* __restrict__ elen,
                                 const int* __restrict__ esrc, const int* __restrict__ tbi,
                                 int* __restrict__ cnt, int* __restrict__ c_ij,
                                 int* __restrict__ c_ka, float* __restrict__ c_cf){
    int t = blockIdx.x*blockDim.x + threadIdx.x;
    int tc = min(t, NTRIPLE-1);
    int ij = tbi[2*tc], ik = tbi[2*tc+1];
    float rij = elen[ij], rik = elen[ik];
    float cc = polycut(rij)*polycut(rik);
    bool valid = (t < NTRIPLE) && (cc != 0.0f);

    float cf[SBF];
    if (valid){
        float ax = evec[ij*3+0], ay = evec[ij*3+1], az = evec[ij*3+2];
        float bx = evec[ik*3+0], by = evec[ik*3+1], bz = evec[ik*3+2];
        float dot = ax*bx + ay*by + az*bz;
        float c = dot/(rij*rik + 1e-12f);
        c = fminf(fmaxf(c, -1.0f + 1e-7f), 1.0f - 1e-7f);
        float a0 = 1.0f, a1 = c, a2 = 2.0f*c*c - 1.0f;
        float x = rik*(PI_F/TBCUT);
        float s1, c1;
        sincosf(x, &s1, &c1);
        float s2 = 2.0f*s1*c1;
        float s3 = s1*(3.0f - 4.0f*s1*s1);
        float inv = 1.0f/(rik + 1e-6f);
        float r0 = s1*inv, r1 = s2*inv, r2 = s3*inv;
        cf[0] = r0*a0*cc; cf[1] = r0*a1*cc; cf[2] = r0*a2*cc;
        cf[3] = r1*a0*cc; cf[4] = r1*a1*cc; cf[5] = r1*a2*cc;
        cf[6] = r2*a0*cc; cf[7] = r2*a1*cc; cf[8] = r2*a2*cc;
    }

    __shared__ int wbase[4];
    __shared__ int gbase;
    int tid = threadIdx.x;
    int wid = tid >> 6, lid = tid & 63;
    unsigned long long m = __ballot(valid);
    int wpre = __popcll(m & ((1ull << lid) - 1ull));
    if (lid == 0) wbase[wid] = __popcll(m);
    __syncthreads();
    if (tid == 0){
        int s = 0;
        #pragma unroll
        for (int i = 0; i < 4; i++){ int v = wbase[i]; wbase[i] = s; s += v; }
        gbase = (s > 0) ? atomicAdd(cnt, s) : 0;
    }
    __syncthreads();
    if (valid){
        int idx = gbase + wbase[wid] + wpre;
        c_ij[idx] = ij;
        c_ka[idx] = esrc[ik];
        float* d = c_cf + (size_t)idx*SBF;
        #pragma unroll
        for (int s = 0; s < SBF; s++) d[s] = cf[s];
    }
}

// ---------------- per-layer: apply compacted triples (grid-stride) ----------------
__global__ void k_triple_apply(const int* __restrict__ cnt, const int* __restrict__ c_ij,
                               const int* __restrict__ c_ka, const float* __restrict__ c_cf,
                               const float* __restrict__ amlp, float* __restrict__ tb_out){
    int n = *cnt;
    for (int t = blockIdx.x*blockDim.x + threadIdx.x; t < n; t += gridDim.x*blockDim.x){
        int ij = c_ij[t], ka = c_ka[t];
        const float* am = amlp + (size_t)ka*SBF;
        const float* cf = c_cf + (size_t)t*SBF;
        float* dst = tb_out + (size_t)ij*SBF;
        #pragma unroll
        for (int s = 0; s < SBF; s++)
            atomicAdd(dst+s, cf[s]*am[s]);
    }
}

// ---------------- fused per-layer gated blocks (ge + ga), all-MFMA ----------------
// Gathers f32 features directly (F has NTOTAL rows for L0; NLOCAL rows + gmap ghost
// resolution for L>=1). feat (bf16 LDS, FSTR): kb0-7 = F[src]|F[dst], kb8-11 = Eh,
// kb12 aux = [rbf | tb9 | 0]. Biases splat-init into accumulators.
// Phase1: ge kb0..12 + ga kb0..7 + te/le. Epi1: E_new -> (Eh if STORE_E) + feat.
// Phase2: ga kb8..11 + la. Epi2: direct f32 atomics into agg[src].
// NO launch_bounds (R5: forcing 5 waves spilled; R7: 64-cap remat-bound).
__global__
void k_gated_fused(const float* __restrict__ F, int gm_on, const int* __restrict__ gmap,
                   ushort* __restrict__ Eh, int store_e,
                   const int* __restrict__ esrc, const int* __restrict__ edst,
                   const float* __restrict__ rbf0, const float* __restrict__ tb_out,
                   const ushort* __restrict__ Wem, const ushort* __restrict__ Weg,
                   const ushort* __restrict__ Wam, const ushort* __restrict__ Wag,
                   const ushort* __restrict__ WxM, const ushort* __restrict__ WxG,
                   const ushort* __restrict__ Ble, const ushort* __restrict__ Bla,
                   const ushort* __restrict__ Bte,
                   const float* __restrict__ btm, const float* __restrict__ btg,
                   const float* __restrict__ bam, const float* __restrict__ bag,
                   const float* __restrict__ tbb, const float* __restrict__ eleb,
                   const float* __restrict__ elab,
                   float* __restrict__ agg){
    __shared__ __align__(16) ushort feat_s[32*FSTR];
    __shared__ int src_s[32];
    __shared__ int dst_s[32];

    const int tid = threadIdx.x;
    const int e0  = blockIdx.x*32;

    if (tid < 32){
        int e = min(e0 + tid, NEDGE-1);
        src_s[tid] = esrc[e];
        int d = edst[e];
        if (gm_on && d >= NLOCAL) d = gmap[d - NLOCAL];
        dst_s[tid] = d;
    }
    __syncthreads();

    // main staging: 32 rows x 48 short8 chunks, 6/thread
    #pragma unroll
    for (int j = 0; j < 6; j++){
        int idx = j*256 + tid;
        int m   = idx/48;
        int k8  = idx - m*48;
        short8 h;
        if (k8 < 32){
            int row = (k8 < 16) ? src_s[m] : dst_s[m];
            int off = (k8 & 15)*8;
            const float4* p = (const float4*)(F + (size_t)row*UNITS + off);
            float4 v0 = p[0], v1 = p[1];
            h[0] = (short)f2bf(v0.x); h[1] = (short)f2bf(v0.y);
            h[2] = (short)f2bf(v0.z); h[3] = (short)f2bf(v0.w);
            h[4] = (short)f2bf(v1.x); h[5] = (short)f2bf(v1.y);
            h[6] = (short)f2bf(v1.z); h[7] = (short)f2bf(v1.w);
        } else {
            int e = min(e0 + m, NEDGE-1);
            h = *(const short8*)(Eh + (size_t)e*UNITS + (k8-32)*8);
        }
        *(short8*)&feat_s[m*FSTR + k8*8] = h;
    }
    // aux staging: 32 rows x 4 short8 = [rbf | tb9 | 0]
    if (tid < 128){
        int m = tid >> 2, j8 = tid & 3;
        int e = min(e0 + m, NEDGE-1);
        short8 h;
        #pragma unroll
        for (int jj = 0; jj < 8; jj++){
            int k = j8*8 + jj;
            float x = 0.0f;
            if (k < 10)      x = rbf0[(size_t)e*NRBF + k];
            else if (k < 19) x = tb_out[(size_t)e*SBF + (k-10)];
            h[jj] = (short)f2bf(x);
        }
        *(short8*)&feat_s[m*FSTR + 384 + j8*8] = h;
    }
    __syncthreads();

    const int lane = tid & 63;
    const int w    = tid >> 6;
    const int quad = lane >> 4;
    const int l15  = lane & 15;

    float btm_c[2], btg_c[2], bam_c[2], bag_c[2], tbb_c[2], leb_c[2];
    #pragma unroll
    for (int ct = 0; ct < 2; ct++){
        int c = w*32 + ct*16 + l15;
        btm_c[ct] = btm[c]; btg_c[ct] = btg[c];
        bam_c[ct] = bam[c]; bag_c[ct] = bag[c];
        tbb_c[ct] = tbb[c]; leb_c[ct] = eleb[c];
    }

    f32x4 acc_em[2][2], acc_eg[2][2], acc_am[2][2], acc_ag[2][2], acc_te[2][2], acc_le[2][2];
    #pragma unroll
    for (int mt = 0; mt < 2; mt++)
        #pragma unroll
        for (int ct = 0; ct < 2; ct++){
            acc_em[mt][ct] = splat4(btm_c[ct]); acc_eg[mt][ct] = splat4(btg_c[ct]);
            acc_am[mt][ct] = splat4(bam_c[ct]); acc_ag[mt][ct] = splat4(bag_c[ct]);
            acc_te[mt][ct] = splat4(tbb_c[ct]); acc_le[mt][ct] = splat4(leb_c[ct]);
        }

    const ushort* a0p = feat_s + l15*FSTR + quad*8;
    const ushort* a1p = a0p + 16*FSTR;

    // Phase 1: ge kb0..11; ga kb0..7
    for (int ks = 0; ks < 12; ks++){
        short8 a0 = *(const short8*)(a0p + ks*32);
        short8 a1 = *(const short8*)(a1p + ks*32);
        #pragma unroll
        for (int ct = 0; ct < 2; ct++){
            int nt = w*2 + ct;
            size_t boff = ((size_t)(ks*8 + nt)*64 + lane)*8;
            short8 b_em = *(const short8*)(Wem + boff);
            short8 b_eg = *(const short8*)(Weg + boff);
            acc_em[0][ct] = __builtin_amdgcn_mfma_f32_16x16x32_bf16(a0, b_em, acc_em[0][ct], 0, 0, 0);
            acc_em[1][ct] = __builtin_amdgcn_mfma_f32_16x16x32_bf16(a1, b_em, acc_em[1][ct], 0, 0, 0);
            acc_eg[0][ct] = __builtin_amdgcn_mfma_f32_16x16x32_bf16(a0, b_eg, acc_eg[0][ct], 0, 0, 0);
            acc_eg[1][ct] = __builtin_amdgcn_mfma_f32_16x16x32_bf16(a1, b_eg, acc_eg[1][ct], 0, 0, 0);
            if (ks < 8){
                short8 b_am = *(const short8*)(Wam + boff);
                short8 b_ag = *(const short8*)(Wag + boff);
                acc_am[0][ct] = __builtin_amdgcn_mfma_f32_16x16x32_bf16(a0, b_am, acc_am[0][ct], 0, 0, 0);
                acc_am[1][ct] = __builtin_amdgcn_mfma_f32_16x16x32_bf16(a1, b_am, acc_am[1][ct], 0, 0, 0);
                acc_ag[0][ct] = __builtin_amdgcn_mfma_f32_16x16x32_bf16(a0, b_ag, acc_ag[0][ct], 0, 0, 0);
                acc_ag[1][ct] = __builtin_amdgcn_mfma_f32_16x16x32_bf16(a1, b_ag, acc_ag[1][ct], 0, 0, 0);
            }
        }
    }
    // kb12 (aux fragment): ge ext + te + le
    short8 a0x = *(const short8*)(a0p + 384);
    short8 a1x = *(const short8*)(a1p + 384);
    #pragma unroll
    for (int ct = 0; ct < 2; ct++){
        size_t bx = ((size_t)(w*2 + ct)*64 + lane)*8;
        short8 b_xm = *(const short8*)(WxM + bx);
        short8 b_xg = *(const short8*)(WxG + bx);
        short8 b_te = *(const short8*)(Bte + bx);
        short8 b_le = *(const short8*)(Ble + bx);
        acc_em[0][ct] = __builtin_amdgcn_mfma_f32_16x16x32_bf16(a0x, b_xm, acc_em[0][ct], 0, 0, 0);
        acc_em[1][ct] = __builtin_amdgcn_mfma_f32_16x16x32_bf16(a1x, b_xm, acc_em[1][ct], 0, 0, 0);
        acc_eg[0][ct] = __builtin_amdgcn_mfma_f32_16x16x32_bf16(a0x, b_xg, acc_eg[0][ct], 0, 0, 0);
        acc_eg[1][ct] = __builtin_amdgcn_mfma_f32_16x16x32_bf16(a1x, b_xg, acc_eg[1][ct], 0, 0, 0);
        acc_te[0][ct] = __builtin_amdgcn_mfma_f32_16x16x32_bf16(a0x, b_te, acc_te[0][ct], 0, 0, 0);
        acc_te[1][ct] = __builtin_amdgcn_mfma_f32_16x16x32_bf16(a1x, b_te, acc_te[1][ct], 0, 0, 0);
        acc_le[0][ct] = __builtin_amdgcn_mfma_f32_16x16x32_bf16(a0x, b_le, acc_le[0][ct], 0, 0, 0);
        acc_le[1][ct] = __builtin_amdgcn_mfma_f32_16x16x32_bf16(a1x, b_le, acc_le[1][ct], 0, 0, 0);
    }

    // Epilogue 1: E_new = E_old + tbgate + gate*el_e
    __syncthreads();
    #pragma unroll
    for (int mt = 0; mt < 2; mt++){
        #pragma unroll
        for (int r = 0; r < 4; r++){
            int ml = mt*16 + quad*4 + r;
            int e  = e0 + ml;
            if (e >= NEDGE) continue;
            #pragma unroll
            for (int ct = 0; ct < 2; ct++){
                int c = w*32 + ct*16 + l15;
                float gate = gatef(acc_em[mt][ct][r], acc_eg[mt][ct][r]);
                float enew = bf2f(feat_s[ml*FSTR + 256 + c])
                           + acc_te[mt][ct][r] + gate*acc_le[mt][ct][r];
                ushort hb = f2bf(enew);
                feat_s[ml*FSTR + 256 + c] = hb;
                if (store_e) Eh[(size_t)e*UNITS + c] = hb;
            }
        }
    }
    __syncthreads();

    // Phase 2: ga kb8..11 on E_new + la
    for (int ks = 8; ks < 12; ks++){
        short8 a0 = *(const short8*)(a0p + ks*32);
        short8 a1 = *(const short8*)(a1p + ks*32);
        #pragma unroll
        for (int ct = 0; ct < 2; ct++){
            int nt = w*2 + ct;
            size_t boff = ((size_t)(ks*8 + nt)*64 + lane)*8;
            short8 b_am = *(const short8*)(Wam + boff);
            short8 b_ag = *(const short8*)(Wag + boff);
            acc_am[0][ct] = __builtin_amdgcn_mfma_f32_16x16x32_bf16(a0, b_am, acc_am[0][ct], 0, 0, 0);
            acc_am[1][ct] = __builtin_amdgcn_mfma_f32_16x16x32_bf16(a1, b_am, acc_am[1][ct], 0, 0, 0);
            acc_ag[0][ct] = __builtin_amdgcn_mfma_f32_16x16x32_bf16(a0, b_ag, acc_ag[0][ct], 0, 0, 0);
            acc_ag[1][ct] = __builtin_amdgcn_mfma_f32_16x16x32_bf16(a1, b_ag, acc_ag[1][ct], 0, 0, 0);
        }
    }
    f32x4 acc_la[2][2];
    #pragma unroll
    for (int ct = 0; ct < 2; ct++){
        float lb = elab[w*32 + ct*16 + l15];
        acc_la[0][ct] = splat4(lb);
        acc_la[1][ct] = splat4(lb);
        size_t bx = ((size_t)(w*2 + ct)*64 + lane)*8;
        short8 b_la = *(const short8*)(Bla + bx);
        acc_la[0][ct] = __builtin_amdgcn_mfma_f32_16x16x32_bf16(a0x, b_la, acc_la[0][ct], 0, 0, 0);
        acc_la[1][ct] = __builtin_amdgcn_mfma_f32_16x16x32_bf16(a1x, b_la, acc_la[1][ct], 0, 0, 0);
    }

    // Epilogue 2: direct f32 atomics into agg[src]
    #pragma unroll
    for (int mt = 0; mt < 2; mt++){
        #pragma unroll
        for (int r = 0; r < 4; r++){
            int ml = mt*16 + quad*4 + r;
            int e  = e0 + ml;
            if (e >= NEDGE) continue;
            #pragma unroll
            for (int ct = 0; ct < 2; ct++){
                int c = w*32 + ct*16 + l15;
                float gate = gatef(acc_am[mt][ct][r], acc_ag[mt][ct][r]);
                atomicAdd(&agg[(size_t)src_s[ml]*UNITS + c], gate*acc_la[mt][ct][r]);
            }
        }
    }
}

// ---------------- final readout + global sum ----------------
__global__ void k_final(const float* __restrict__ A, const float* __restrict__ W1,
                        const float* __restrict__ b1, const float* __restrict__ W2,
                        const float* __restrict__ b2, const int* __restrict__ anum,
                        const float* __restrict__ escl, const float* __restrict__ eshf,
                        float* __restrict__ out){
    __shared__ float red[256];
    const int tid  = threadIdx.x;
    const int c    = tid & 127;
    const int half = tid >> 7;
    float b1c = b1[c];
    float w2c = W2[c];
    float b2v = b2[0];
    float tpart = 0.0f;
    const int npairs = NLOCAL/2;
    for (int p = blockIdx.x; p < npairs; p += gridDim.x){
        int a = 2*p + half;
        const float* h = A + (size_t)a*UNITS;
        float acc = b1c;
        for (int k = 0; k < UNITS; k++)
            acc = fmaf(h[k], W1[k*UNITS + c], acc);
        float hid = silu(acc);
        int z = anum[a];
        float sc = escl[z];
        tpart = fmaf(sc*hid, w2c, tpart);
        if (c == 0) tpart += sc*b2v + eshf[z];
    }
    red[tid] = tpart;
    __syncthreads();
    for (int s = 128; s > 0; s >>= 1){
        if (tid < s) red[tid] += red[tid + s];
        __syncthreads();
    }
    if (tid == 0) atomicAdd(out, red[0]);
}

extern "C" void kernel_launch(void* const* d_in, const int* in_sizes, int n_in,
                              void* d_out, int out_size, void* d_ws, size_t ws_size,
                              hipStream_t stream){
    const int*   anum  = (const int*)d_in[0];
    const float* pos   = (const float*)d_in[1];
    const float* cell  = (const float*)d_in[2];
    const float* pbc   = (const float*)d_in[3];
    const int*   esrc  = (const int*)d_in[4];
    const int*   edst  = (const int*)d_in[5];
    const int*   tbi   = (const int*)d_in[6];
    const int*   batch = (const int*)d_in[7];
    const int*   gmap  = (const int*)d_in[8];
    const float* embw  = (const float*)d_in[10];
    const float* encw  = (const float*)d_in[11];
    const float* encb  = (const float*)d_in[12];
    const float* tbaw  = (const float*)d_in[13];
    const float* tbab  = (const float*)d_in[14];
    const float* tbgw  = (const float*)d_in[15];
    const float* tbgb  = (const float*)d_in[16];
    const float* gewm  = (const float*)d_in[17];
    const float* gebm  = (const float*)d_in[18];
    const float* gewg  = (const float*)d_in[19];
    const float* gebg  = (const float*)d_in[20];
    const float* elew  = (const float*)d_in[21];
    const float* eleb  = (const float*)d_in[22];
    const float* gawm  = (const float*)d_in[23];
    const float* gabm  = (const float*)d_in[24];
    const float* gawg  = (const float*)d_in[25];
    const float* gabg  = (const float*)d_in[26];
    const float* elaw  = (const float*)d_in[27];
    const float* elab  = (const float*)d_in[28];
    const float* fw1   = (const float*)d_in[29];
    const float* fb1   = (const float*)d_in[30];
    const float* fw2   = (const float*)d_in[31];
    const float* fb2   = (const float*)d_in[32];
    const float* escl  = (const float*)d_in[33];
    const float* eshf  = (const float*)d_in[34];
    (void)in_sizes; (void)n_in; (void)out_size; (void)ws_size;

    float* ws     = (float*)d_ws;
    float* embedF = ws;                                   // NTOTAL*128 f32
    float* aggA   = embedF + (size_t)NTOTAL*UNITS;        // NLOCAL*128 f32
    float* aggB   = aggA   + (size_t)NLOCAL*UNITS;        // NLOCAL*128 f32
    float* evec   = aggB   + (size_t)NLOCAL*UNITS;        // NEDGE*3
    float* elen   = evec   + (size_t)NEDGE*3;             // NEDGE
    float* rbf0   = elen   + (size_t)NEDGE;               // NEDGE*10
    float* tbout  = rbf0   + (size_t)NEDGE*NRBF;          // NEDGE*9
    float* amlp   = tbout  + (size_t)NEDGE*SBF;           // NLOCAL*9
    float* btot   = amlp   + (size_t)NLOCAL*SBF;          // 3*2*128
    int*   tcnt   = (int*)(btot + 3*2*128);               // 1 (+3 pad)
    int*   c_ij   = tcnt + 4;                             // NTRIPLE
    int*   c_ka   = c_ij + NTRIPLE;                       // NTRIPLE
    float* c_cf   = (float*)(c_ka + NTRIPLE);             // 9*NTRIPLE (AoS)
    ushort* edgeEh = (ushort*)(c_cf + (size_t)9*NTRIPLE); // NEDGE*128 bf16
    ushort* wmain  = edgeEh + (size_t)NEDGE*UNITS;        // 3*4*49152
    ushort* wext   = wmain + (size_t)3*4*49152;           // 3*2*4096
    ushort* waux   = wext  + (size_t)3*2*4096;            // 3*3*4096

    float* out = (float*)d_out;
    hipMemsetAsync(out, 0, sizeof(float), stream);
    hipMemsetAsync(tcnt, 0, sizeof(int), stream);

    k_pack_w   <<<(3*4*12*8*64 + 255)/256, 256, 0, stream>>>(gewm, gewg, gawm, gawg, wmain);
    k_pack_ext <<<(3*2*512 + 255)/256, 256, 0, stream>>>(gewm, gewg, tbgw, wext);
    k_pack_aux <<<(3*3*512 + 255)/256, 256, 0, stream>>>(elew, elaw, tbgw, waux);
    k_pack_bias<<<(3*2*128 + 255)/256, 256, 0, stream>>>(gewm, gewg, gebm, gebg, tbgb, btot);
    k_edge_geom<<<(NEDGE+255)/256, 256, 0, stream>>>(pos, cell, pbc, esrc, edst, batch,
                                                     evec, elen, rbf0);
    k_embed<<<(NTOTAL*32+255)/256, 256, 0, stream>>>(anum, embw, embedF);
    k_edge_enc<<<(NEDGE*32+255)/256, 256, 0, stream>>>(rbf0, encw, encb, edgeEh);
    k_triple_compact<<<(NTRIPLE+255)/256, 256, 0, stream>>>(evec, elen, esrc, tbi,
                                                            tcnt, c_ij, c_ka, c_cf);

    const int gemm_blocks = (NEDGE+31)/32;
    float* Fin[3]    = { embedF, aggA, aggB };
    float* Aout[3]   = { aggA,   aggB, aggA };
    for (int L = 0; L < NLAYERS; L++){
        const ushort* wmL = wmain + (size_t)L*4*49152;
        const ushort* wxL = wext  + (size_t)L*2*4096;
        const ushort* waL = waux  + (size_t)L*3*4096;
        k_tb_mlp<<<(NLOCAL+255)/256, 256, 0, stream>>>(Fin[L],
            tbaw + (size_t)L*UNITS*SBF, tbab + (size_t)L*SBF, amlp, Aout[L]);
        hipMemsetAsync(tbout, 0, (size_t)NEDGE*SBF*sizeof(float), stream);
        k_triple_apply<<<512, 256, 0, stream>>>(tcnt, c_ij, c_ka, c_cf, amlp, tbout);
        k_gated_fused<<<gemm_blocks, 256, 0, stream>>>(Fin[L], (L > 0) ? 1 : 0, gmap,
            edgeEh, (L < NLAYERS-1) ? 1 : 0,
            esrc, edst, rbf0, tbout,
            wmL + 0*49152, wmL + 1*49152, wmL + 2*49152, wmL + 3*49152,
            wxL + 0*4096,  wxL + 1*4096,
            waL + 0*4096,  waL + 1*4096, waL + 2*4096,
            btot + (size_t)L*2*128, btot + (size_t)L*2*128 + 128,
            gabm + (size_t)L*UNITS, gabg + (size_t)L*UNITS,
            tbgb + (size_t)L*UNITS, eleb + (size_t)L*UNITS, elab + (size_t)L*UNITS,
            Aout[L]);
    }
    k_final<<<1024, 256, 0, stream>>>(aggA, fw1, fb1, fw2, fb2, anum, escl, eshf, out);
}

// Round 12
// 1329.995 us; speedup vs baseline: 1.1191x; 1.0089x over previous
//
#include <hip/hip_runtime.h>
#include <math.h>

#define UNITS   128
#define NRBF    10
#define SBF     9
#define NLAYERS 3
#define NELEM   95
#define NTOTAL  60000
#define NLOCAL  50000
#define NGHOST  10000
#define NEDGE   250000
#define NTRIPLE 1000000
#define CUTOFF  5.0f
#define TBCUT   4.0f
#define PI_F    3.14159265358979323846f
#define FSTR    424   // feat row stride in ushorts: 13 kb * 32 + 8 pad
#define MEDGE   64    // edges per gated block

typedef __attribute__((ext_vector_type(8))) short short8;
typedef __attribute__((ext_vector_type(4))) float f32x4;

__device__ __forceinline__ float sigm(float x){ return 1.0f/(1.0f+__expf(-x)); }
__device__ __forceinline__ float silu(float x){ return x/(1.0f+__expf(-x)); }
__device__ __forceinline__ float polycut(float r){
    float q = r*(1.0f/TBCUT);
    float q2 = q*q, q3 = q2*q;
    float p = 1.0f - 6.0f*q2*q3 + 15.0f*q2*q2 - 10.0f*q3;
    return (r <= TBCUT) ? p : 0.0f;
}
__device__ __forceinline__ ushort f2bf(float x){
    unsigned u = __float_as_uint(x);
    unsigned r = (u + 0x7fffu + ((u>>16)&1u)) >> 16;
    return (ushort)r;
}
__device__ __forceinline__ float bf2f(ushort h){
    return __uint_as_float(((unsigned)h) << 16);
}
__device__ __forceinline__ void fma4s(float4& acc, float s, const float4& v){
    acc.x = fmaf(s, v.x, acc.x);
    acc.y = fmaf(s, v.y, acc.y);
    acc.z = fmaf(s, v.z, acc.z);
    acc.w = fmaf(s, v.w, acc.w);
}
__device__ __forceinline__ f32x4 splat4(float x){ f32x4 v = {x,x,x,x}; return v; }
__device__ __forceinline__ float gatef(float xm, float xg){
    float d = (1.0f+__expf(-xm))*(1.0f+__expf(-xg));
    return xm*__builtin_amdgcn_rcpf(d);
}

// ---------------- edge geometry + rbf ----------------
__global__ void k_edge_geom(const float* __restrict__ pos, const float* __restrict__ cell,
                            const float* __restrict__ pbc, const int* __restrict__ src,
                            const int* __restrict__ dst, const int* __restrict__ batch,
                            float* __restrict__ evec, float* __restrict__ elen,
                            float* __restrict__ rbf0){
    int e = blockIdx.x*blockDim.x + threadIdx.x;
    if (e >= NEDGE) return;
    int s = src[e], d = dst[e];
    int b = batch[s];
    const float* C = cell + b*9;
    float p0 = pbc[e*3+0], p1 = pbc[e*3+1], p2 = pbc[e*3+2];
    float vx = pos[s*3+0] - (pos[d*3+0] + p0*C[0] + p1*C[3] + p2*C[6]);
    float vy = pos[s*3+1] - (pos[d*3+1] + p0*C[1] + p1*C[4] + p2*C[7]);
    float vz = pos[s*3+2] - (pos[d*3+2] + p0*C[2] + p1*C[5] + p2*C[8]);
    float r = sqrtf(vx*vx + vy*vy + vz*vz);
    evec[e*3+0] = vx; evec[e*3+1] = vy; evec[e*3+2] = vz;
    elen[e] = r;
    #pragma unroll
    for (int i = 0; i < NRBF; i++){
        float mu = (CUTOFF/(NRBF-1))*i;
        float dm = r - mu;
        rbf0[e*NRBF + i] = __expf(-dm*dm*2.0f);
    }
}

// ---------------- atom embedding gather (f32 + NTOTAL bf16 mirror for L0 gathers) ----------------
__global__ void k_embed(const int* __restrict__ anum, const float* __restrict__ embw,
                        float* __restrict__ A, ushort* __restrict__ Ah){
    int t = blockIdx.x*blockDim.x + threadIdx.x;
    if (t >= NTOTAL*32) return;
    int a = t >> 5, q = t & 31;
    float4 v = ((const float4*)embw)[anum[a]*32 + q];
    ((float4*)A)[t] = v;
    ushort4 h;
    h.x = f2bf(v.x); h.y = f2bf(v.y); h.z = f2bf(v.z); h.w = f2bf(v.w);
    ((ushort4*)Ah)[t] = h;
}

// ---------------- edge encoding: Eh = bf16(rbf0 @ Wenc + benc) ----------------
__global__ void k_edge_enc(const float* __restrict__ rbf0, const float* __restrict__ encw,
                           const float* __restrict__ encb, ushort* __restrict__ Eh){
    int t = blockIdx.x*blockDim.x + threadIdx.x;
    if (t >= NEDGE*32) return;
    int e = t >> 5, q = t & 31;
    float4 acc = ((const float4*)encb)[q];
    const float4* W4 = (const float4*)encw;
    #pragma unroll
    for (int r = 0; r < NRBF; r++){
        float rv = rbf0[e*NRBF + r];
        fma4s(acc, rv, W4[r*32 + q]);
    }
    ushort4 h;
    h.x = f2bf(acc.x); h.y = f2bf(acc.y); h.z = f2bf(acc.z); h.w = f2bf(acc.w);
    ((ushort4*)Eh)[t] = h;
}

// ---------------- pack main gated-MLP weights: [L][mat:4][kb:12][nt:8][lane:64][j:8] ----------------
__global__ void k_pack_w(const float* __restrict__ gewm, const float* __restrict__ gewg,
                         const float* __restrict__ gawm, const float* __restrict__ gawg,
                         ushort* __restrict__ wp){
    int t = blockIdx.x*blockDim.x + threadIdx.x;
    if (t >= 3*4*12*8*64) return;
    int lane = t & 63;
    int nt   = (t>>6) & 7;
    int rest = t >> 9;
    int kb   = rest % 12;
    int r2   = rest / 12;
    int mat  = r2 & 3;
    int L    = r2 >> 2;
    const float* src;
    if      (mat == 0) src = gewm;
    else if (mat == 1) src = gewg;
    else if (mat == 2) src = gawm;
    else               src = gawg;
    src += (size_t)L*384*128;
    int n = nt*16 + (lane & 15);
    int kbase = kb*32 + (lane>>4)*8;
    ushort* dst = wp + (size_t)t*8;
    #pragma unroll
    for (int j = 0; j < 8; j++) dst[j] = f2bf(src[(size_t)(kbase+j)*128 + n]);
}

// ---------------- pack kb12 ext weights: (tbgw @ W_E) rows at aux k=10..18 ----------------
__global__ void k_pack_ext(const float* __restrict__ gewm, const float* __restrict__ gewg,
                           const float* __restrict__ tbg, ushort* __restrict__ wext){
    int t = blockIdx.x*blockDim.x + threadIdx.x;
    if (t >= 3*2*512) return;
    int lane = t & 63;
    int nt   = (t>>6) & 7;
    int mat  = (t>>9) & 1;
    int L    = t >> 10;
    const float* W = ((mat==0)? gewm : gewg) + (size_t)L*384*128;
    const float* tg = tbg + (size_t)L*SBF*UNITS;
    int n = nt*16 + (lane & 15);
    ushort* dst = wext + (size_t)t*8;
    #pragma unroll
    for (int j = 0; j < 8; j++){
        int k = (lane>>4)*8 + j;
        float v = 0.0f;
        if (k >= 10 && k <= 18){
            int s = k - 10;
            for (int kk = 0; kk < 128; kk++)
                v = fmaf(tg[s*UNITS+kk], W[(size_t)(256+kk)*128 + n], v);
        }
        dst[j] = f2bf(v);
    }
}

// ---------------- pack aux B mats: el_e, el_a, tbgate ----------------
__global__ void k_pack_aux(const float* __restrict__ elew, const float* __restrict__ elaw,
                           const float* __restrict__ tbg, ushort* __restrict__ waux){
    int t = blockIdx.x*blockDim.x + threadIdx.x;
    if (t >= 3*3*512) return;
    int lane = t & 63;
    int nt   = (t>>6) & 7;
    int rest = t >> 9;
    int mat  = rest % 3;
    int L    = rest / 3;
    int n = nt*16 + (lane & 15);
    ushort* dst = waux + (size_t)t*8;
    #pragma unroll
    for (int j = 0; j < 8; j++){
        int k = (lane>>4)*8 + j;
        float v = 0.0f;
        if (mat == 0){ if (k < 10) v = elew[(size_t)L*NRBF*UNITS + k*UNITS + n]; }
        else if (mat == 1){ if (k < 10) v = elaw[(size_t)L*NRBF*UNITS + k*UNITS + n]; }
        else { if (k >= 10 && k <= 18) v = tbg[(size_t)L*SBF*UNITS + (k-10)*UNITS + n]; }
        dst[j] = f2bf(v);
    }
}

// ---------------- bias totals: btot[L][mat:2][128] = be + tbb @ W_E ----------------
__global__ void k_pack_bias(const float* __restrict__ gewm, const float* __restrict__ gewg,
                            const float* __restrict__ gebm, const float* __restrict__ gebg,
                            const float* __restrict__ tbb, float* __restrict__ btot){
    int t = blockIdx.x*blockDim.x + threadIdx.x;
    if (t >= 3*2*128) return;
    int n = t & 127;
    int mat = (t>>7) & 1;
    int L = t >> 8;
    const float* W = ((mat==0)? gewm : gewg) + (size_t)L*384*128;
    const float* be = ((mat==0)? gebm : gebg) + (size_t)L*UNITS;
    const float* tb = tbb + (size_t)L*UNITS;
    float v = be[n];
    for (int kk = 0; kk < 128; kk++)
        v = fmaf(tb[kk], W[(size_t)(256+kk)*128 + n], v);
    btot[t] = v;
}

// ---------------- per-layer: atom sbf mlp + seed aggOut + write bf16 mirror of Fin ----------------
__global__ void k_tb_mlp(const float* __restrict__ Fin, const float* __restrict__ W,
                         const float* __restrict__ b, float* __restrict__ out,
                         float* __restrict__ aggOut, ushort* __restrict__ Ah){
    int a = blockIdx.x*blockDim.x + threadIdx.x;
    if (a >= NLOCAL) return;
    float acc[SBF];
    #pragma unroll
    for (int s = 0; s < SBF; s++) acc[s] = b[s];
    const float4* row4 = (const float4*)(Fin + (size_t)a*UNITS);
    float4* agg4 = (float4*)(aggOut + (size_t)a*UNITS);
    ushort4* ah4 = (ushort4*)(Ah + (size_t)a*UNITS);
    for (int k4 = 0; k4 < 32; k4++){
        float4 v = row4[k4];
        agg4[k4] = v;
        ushort4 h;
        h.x = f2bf(v.x); h.y = f2bf(v.y); h.z = f2bf(v.z); h.w = f2bf(v.w);
        ah4[k4] = h;
        const float* w = W + (k4*4)*SBF;
        #pragma unroll
        for (int s = 0; s < SBF; s++){
            acc[s] = fmaf(v.x, w[s],        acc[s]);
            acc[s] = fmaf(v.y, w[s+SBF],    acc[s]);
            acc[s] = fmaf(v.z, w[s+2*SBF],  acc[s]);
            acc[s] = fmaf(v.w, w[s+3*SBF],  acc[s]);
        }
    }
    #pragma unroll
    for (int s = 0; s < SBF; s++) out[a*SBF + s] = sigm(acc[s]);
}

// ---------------- one-time triple compaction: block-aggregated counter ----------------
__global__ void k_triple_compact(const float* __restrict__ evec, const float* __restrict__ elen,
                                 const int* __restrict__ esrc, const int* __restrict__ tbi,
                                 int* __restrict__ cnt, int* __restrict__ c_ij,
                                 int* __restrict__ c_ka, float* __restrict__ c_cf){
    int t = blockIdx.x*blockDim.x + threadIdx.x;
    int tc = min(t, NTRIPLE-1);
    int ij = tbi[2*tc], ik = tbi[2*tc+1];
    float rij = elen[ij], rik = elen[ik];
    float cc = polycut(rij)*polycut(rik);
    bool valid = (t < NTRIPLE) && (cc != 0.0f);

    float cf[SBF];
    if (valid){
        float ax = evec[ij*3+0], ay = evec[ij*3+1], az = evec[ij*3+2];
        float bx = evec[ik*3+0], by = evec[ik*3+1], bz = evec[ik*3+2];
        float dot = ax*bx + ay*by + az*bz;
        float c = dot/(rij*rik + 1e-12f);
        c = fminf(fmaxf(c, -1.0f + 1e-7f), 1.0f - 1e-7f);
        float a0 = 1.0f, a1 = c, a2 = 2.0f*c*c - 1.0f;
        float x = rik*(PI_F/TBCUT);
        float s1, c1;
        sincosf(x, &s1, &c1);
        float s2 = 2.0f*s1*c1;
        float s3 = s1*(3.0f - 4.0f*s1*s1);
        float inv = 1.0f/(rik + 1e-6f);
        float r0 = s1*inv, r1 = s2*inv, r2 = s3*inv;
        cf[0] = r0*a0*cc; cf[1] = r0*a1*cc; cf[2] = r0*a2*cc;
        cf[3] = r1*a0*cc; cf[4] = r1*a1*cc; cf[5] = r1*a2*cc;
        cf[6] = r2*a0*cc; cf[7] = r2*a1*cc; cf[8] = r2*a2*cc;
    }

    __shared__ int wbase[4];
    __shared__ int gbase;
    int tid = threadIdx.x;
    int wid = tid >> 6, lid = tid & 63;
    unsigned long long m = __ballot(valid);
    int wpre = __popcll(m & ((1ull << lid) - 1ull));
    if (lid == 0) wbase[wid] = __popcll(m);
    __syncthreads();
    if (tid == 0){
        int s = 0;
        #pragma unroll
        for (int i = 0; i < 4; i++){ int v = wbase[i]; wbase[i] = s; s += v; }
        gbase = (s > 0) ? atomicAdd(cnt, s) : 0;
    }
    __syncthreads();
    if (valid){
        int idx = gbase + wbase[wid] + wpre;
        c_ij[idx] = ij;
        c_ka[idx] = esrc[ik];
        float* d = c_cf + (size_t)idx*SBF;
        #pragma unroll
        for (int s = 0; s < SBF; s++) d[s] = cf[s];
    }
}

// ---------------- per-layer: apply compacted triples (grid-stride) ----------------
__global__ void k_triple_apply(const int* __restrict__ cnt, const int* __restrict__ c_ij,
                               const int* __restrict__ c_ka, const float* __restrict__ c_cf,
                               const float* __restrict__ amlp, float* __restrict__ tb_out){
    int n = *cnt;
    for (int t = blockIdx.x*blockDim.x + threadIdx.x; t < n; t += gridDim.x*blockDim.x){
        int ij = c_ij[t], ka = c_ka[t];
        const float* am = amlp + (size_t)ka*SBF;
        const float* cf = c_cf + (size_t)t*SBF;
        float* dst = tb_out + (size_t)ij*SBF;
        #pragma unroll
        for (int s = 0; s < SBF; s++)
            atomicAdd(dst+s, cf[s]*am[s]);
    }
}

// ---------------- fused per-layer gated blocks (ge + ga), all-MFMA ----------------
// 64 edges/block, 512 threads (8 waves); wave w owns output cols [16w,16w+16) (nt=w).
// Halves per-edge B-fragment L2 traffic vs 32-edge blocks (R11 analysis: ~90us -> ~45us).
// bf16 gathers from Ah mirror (NTOTAL for L0, NLOCAL + gmap-resolved dst for L>=1).
// Phase1 = ge only (em,eg,te,le live: 16 f32x4); Epi1: E_new -> feat (+Eh if store_e);
// Phase2 = ga full-K (am,ag,la live: 12 f32x4) -- same MFMA count, lower peak VGPR.
// NO launch_bounds (R5: forcing waves spilled; R7: tight cap remat-bound).
__global__
void k_gated_fused(const ushort* __restrict__ Ah, int gm_on, const int* __restrict__ gmap,
                   ushort* __restrict__ Eh, int store_e,
                   const int* __restrict__ esrc, const int* __restrict__ edst,
                   const float* __restrict__ rbf0, const float* __restrict__ tb_out,
                   const ushort* __restrict__ Wem, const ushort* __restrict__ Weg,
                   const ushort* __restrict__ Wam, const ushort* __restrict__ Wag,
                   const ushort* __restrict__ WxM, const ushort* __restrict__ WxG,
                   const ushort* __restrict__ Ble, const ushort* __restrict__ Bla,
                   const ushort* __restrict__ Bte,
                   const float* __restrict__ btm, const float* __restrict__ btg,
                   const float* __restrict__ bam, const float* __restrict__ bag,
                   const float* __restrict__ tbb, const float* __restrict__ eleb,
                   const float* __restrict__ elab,
                   float* __restrict__ agg){
    __shared__ __align__(16) ushort feat_s[MEDGE*FSTR];
    __shared__ int src_s[MEDGE];
    __shared__ int dst_s[MEDGE];

    const int tid = threadIdx.x;
    const int e0  = blockIdx.x*MEDGE;

    if (tid < MEDGE){
        int e = min(e0 + tid, NEDGE-1);
        src_s[tid] = esrc[e];
        int d = edst[e];
        if (gm_on && d >= NLOCAL) d = gmap[d - NLOCAL];
        dst_s[tid] = d;
    }
    __syncthreads();

    // main staging: 64 rows x 48 short8 chunks, pure bf16 copies, 6/thread
    #pragma unroll
    for (int j = 0; j < 6; j++){
        int idx = j*512 + tid;
        int m   = idx/48;
        int k8  = idx - m*48;
        const ushort* p;
        if (k8 < 16)      p = Ah + (size_t)src_s[m]*UNITS + k8*8;
        else if (k8 < 32) p = Ah + (size_t)dst_s[m]*UNITS + (k8-16)*8;
        else {
            int e = min(e0 + m, NEDGE-1);
            p = Eh + (size_t)e*UNITS + (k8-32)*8;
        }
        *(short8*)&feat_s[m*FSTR + k8*8] = *(const short8*)p;
    }
    // aux staging: 64 rows x 4 short8 = [rbf | tb9 | 0]
    if (tid < 256){
        int m = tid >> 2, j8 = tid & 3;
        int e = min(e0 + m, NEDGE-1);
        short8 h;
        #pragma unroll
        for (int jj = 0; jj < 8; jj++){
            int k = j8*8 + jj;
            float x = 0.0f;
            if (k < 10)      x = rbf0[(size_t)e*NRBF + k];
            else if (k < 19) x = tb_out[(size_t)e*SBF + (k-10)];
            h[jj] = (short)f2bf(x);
        }
        *(short8*)&feat_s[m*FSTR + 384 + j8*8] = h;
    }
    __syncthreads();

    const int lane = tid & 63;
    const int w    = tid >> 6;        // 0..7 = output col tile (nt)
    const int quad = lane >> 4;
    const int l15  = lane & 15;
    const int c    = w*16 + l15;      // this thread's output column

    // ---------------- Phase 1: ge GEMM (kb0..12) + te/le aux ----------------
    f32x4 acc_em[4], acc_eg[4], acc_te[4], acc_le[4];
    {
        float bm = btm[c], bg = btg[c], tb = tbb[c], le = eleb[c];
        #pragma unroll
        for (int mt = 0; mt < 4; mt++){
            acc_em[mt] = splat4(bm); acc_eg[mt] = splat4(bg);
            acc_te[mt] = splat4(tb); acc_le[mt] = splat4(le);
        }
    }
    const ushort* abase = feat_s + l15*FSTR + quad*8;

    for (int ks = 0; ks < 12; ks++){
        short8 a[4];
        #pragma unroll
        for (int mt = 0; mt < 4; mt++)
            a[mt] = *(const short8*)(abase + mt*16*FSTR + ks*32);
        size_t boff = ((size_t)(ks*8 + w)*64 + lane)*8;
        short8 b_em = *(const short8*)(Wem + boff);
        short8 b_eg = *(const short8*)(Weg + boff);
        #pragma unroll
        for (int mt = 0; mt < 4; mt++){
            acc_em[mt] = __builtin_amdgcn_mfma_f32_16x16x32_bf16(a[mt], b_em, acc_em[mt], 0, 0, 0);
            acc_eg[mt] = __builtin_amdgcn_mfma_f32_16x16x32_bf16(a[mt], b_eg, acc_eg[mt], 0, 0, 0);
        }
    }
    {   // kb12 aux fragment
        size_t bx = ((size_t)w*64 + lane)*8;
        short8 b_xm = *(const short8*)(WxM + bx);
        short8 b_xg = *(const short8*)(WxG + bx);
        short8 b_te = *(const short8*)(Bte + bx);
        short8 b_le = *(const short8*)(Ble + bx);
        #pragma unroll
        for (int mt = 0; mt < 4; mt++){
            short8 ax = *(const short8*)(abase + mt*16*FSTR + 384);
            acc_em[mt] = __builtin_amdgcn_mfma_f32_16x16x32_bf16(ax, b_xm, acc_em[mt], 0, 0, 0);
            acc_eg[mt] = __builtin_amdgcn_mfma_f32_16x16x32_bf16(ax, b_xg, acc_eg[mt], 0, 0, 0);
            acc_te[mt] = __builtin_amdgcn_mfma_f32_16x16x32_bf16(ax, b_te, acc_te[mt], 0, 0, 0);
            acc_le[mt] = __builtin_amdgcn_mfma_f32_16x16x32_bf16(ax, b_le, acc_le[mt], 0, 0, 0);
        }
    }

    // ---------------- Epilogue 1: E_new = E_old + tbgate + gate*el_e ----------------
    __syncthreads();
    #pragma unroll
    for (int mt = 0; mt < 4; mt++){
        #pragma unroll
        for (int r = 0; r < 4; r++){
            int ml = mt*16 + quad*4 + r;
            int e  = e0 + ml;
            if (e >= NEDGE) continue;
            float gate = gatef(acc_em[mt][r], acc_eg[mt][r]);
            float enew = bf2f(feat_s[ml*FSTR + 256 + c])
                       + acc_te[mt][r] + gate*acc_le[mt][r];
            ushort hb = f2bf(enew);
            feat_s[ml*FSTR + 256 + c] = hb;
            if (store_e) Eh[(size_t)e*UNITS + c] = hb;
        }
    }
    __syncthreads();

    // ---------------- Phase 2: ga GEMM (full kb0..11 on E_new) + la aux ----------------
    f32x4 acc_am[4], acc_ag[4], acc_la[4];
    {
        float bm = bam[c], bg = bag[c], lb = elab[c];
        #pragma unroll
        for (int mt = 0; mt < 4; mt++){
            acc_am[mt] = splat4(bm); acc_ag[mt] = splat4(bg); acc_la[mt] = splat4(lb);
        }
    }
    for (int ks = 0; ks < 12; ks++){
        short8 a[4];
        #pragma unroll
        for (int mt = 0; mt < 4; mt++)
            a[mt] = *(const short8*)(abase + mt*16*FSTR + ks*32);
        size_t boff = ((size_t)(ks*8 + w)*64 + lane)*8;
        short8 b_am = *(const short8*)(Wam + boff);
        short8 b_ag = *(const short8*)(Wag + boff);
        #pragma unroll
        for (int mt = 0; mt < 4; mt++){
            acc_am[mt] = __builtin_amdgcn_mfma_f32_16x16x32_bf16(a[mt], b_am, acc_am[mt], 0, 0, 0);
            acc_ag[mt] = __builtin_amdgcn_mfma_f32_16x16x32_bf16(a[mt], b_ag, acc_ag[mt], 0, 0, 0);
        }
    }
    {
        size_t bx = ((size_t)w*64 + lane)*8;
        short8 b_la = *(const short8*)(Bla + bx);
        #pragma unroll
        for (int mt = 0; mt < 4; mt++){
            short8 ax = *(const short8*)(abase + mt*16*FSTR + 384);
            acc_la[mt] = __builtin_amdgcn_mfma_f32_16x16x32_bf16(ax, b_la, acc_la[mt], 0, 0, 0);
        }
    }

    // ---------------- Epilogue 2: f32 atomics into agg[src] ----------------
    #pragma unroll
    for (int mt = 0; mt < 4; mt++){
        #pragma unroll
        for (int r = 0; r < 4; r++){
            int ml = mt*16 + quad*4 + r;
            int e  = e0 + ml;
            if (e >= NEDGE) continue;
            float gate = gatef(acc_am[mt][r], acc_ag[mt][r]);
            atomicAdd(&agg[(size_t)src_s[ml]*UNITS + c], gate*acc_la[mt][r]);
        }
    }
}

// ---------------- final readout + global sum ----------------
__global__ void k_final(const float* __restrict__ A, const float* __restrict__ W1,
                        const float* __restrict__ b1, const float* __restrict__ W2,
                        const float* __restrict__ b2, const int* __restrict__ anum,
                        const float* __restrict__ escl, const float* __restrict__ eshf,
                        float* __restrict__ out){
    __shared__ float red[256];
    const int tid  = threadIdx.x;
    const int c    = tid & 127;
    const int half = tid >> 7;
    float b1c = b1[c];
    float w2c = W2[c];
    float b2v = b2[0];
    float tpart = 0.0f;
    const int npairs = NLOCAL/2;
    for (int p = blockIdx.x; p < npairs; p += gridDim.x){
        int a = 2*p + half;
        const float* h = A + (size_t)a*UNITS;
        float acc = b1c;
        for (int k = 0; k < UNITS; k++)
            acc = fmaf(h[k], W1[k*UNITS + c], acc);
        float hid = silu(acc);
        int z = anum[a];
        float sc = escl[z];
        tpart = fmaf(sc*hid, w2c, tpart);
        if (c == 0) tpart += sc*b2v + eshf[z];
    }
    red[tid] = tpart;
    __syncthreads();
    for (int s = 128; s > 0; s >>= 1){
        if (tid < s) red[tid] += red[tid + s];
        __syncthreads();
    }
    if (tid == 0) atomicAdd(out, red[0]);
}

extern "C" void kernel_launch(void* const* d_in, const int* in_sizes, int n_in,
                              void* d_out, int out_size, void* d_ws, size_t ws_size,
                              hipStream_t stream){
    const int*   anum  = (const int*)d_in[0];
    const float* pos   = (const float*)d_in[1];
    const float* cell  = (const float*)d_in[2];
    const float* pbc   = (const float*)d_in[3];
    const int*   esrc  = (const int*)d_in[4];
    const int*   edst  = (const int*)d_in[5];
    const int*   tbi   = (const int*)d_in[6];
    const int*   batch = (const int*)d_in[7];
    const int*   gmap  = (const int*)d_in[8];
    const float* embw  = (const float*)d_in[10];
    const float* encw  = (const float*)d_in[11];
    const float* encb  = (const float*)d_in[12];
    const float* tbaw  = (const float*)d_in[13];
    const float* tbab  = (const float*)d_in[14];
    const float* tbgw  = (const float*)d_in[15];
    const float* tbgb  = (const float*)d_in[16];
    const float* gewm  = (const float*)d_in[17];
    const float* gebm  = (const float*)d_in[18];
    const float* gewg  = (const float*)d_in[19];
    const float* gebg  = (const float*)d_in[20];
    const float* elew  = (const float*)d_in[21];
    const float* eleb  = (const float*)d_in[22];
    const float* gawm  = (const float*)d_in[23];
    const float* gabm  = (const float*)d_in[24];
    const float* gawg  = (const float*)d_in[25];
    const float* gabg  = (const float*)d_in[26];
    const float* elaw  = (const float*)d_in[27];
    const float* elab  = (const float*)d_in[28];
    const float* fw1   = (const float*)d_in[29];
    const float* fb1   = (const float*)d_in[30];
    const float* fw2   = (const float*)d_in[31];
    const float* fb2   = (const float*)d_in[32];
    const float* escl  = (const float*)d_in[33];
    const float* eshf  = (const float*)d_in[34];
    (void)in_sizes; (void)n_in; (void)out_size; (void)ws_size;

    float* ws     = (float*)d_ws;
    float* embedF = ws;                                   // NTOTAL*128 f32
    float* aggA   = embedF + (size_t)NTOTAL*UNITS;        // NLOCAL*128 f32
    float* aggB   = aggA   + (size_t)NLOCAL*UNITS;        // NLOCAL*128 f32
    float* evec   = aggB   + (size_t)NLOCAL*UNITS;        // NEDGE*3
    float* elen   = evec   + (size_t)NEDGE*3;             // NEDGE
    float* rbf0   = elen   + (size_t)NEDGE;               // NEDGE*10
    float* tbout  = rbf0   + (size_t)NEDGE*NRBF;          // NEDGE*9
    float* amlp   = tbout  + (size_t)NEDGE*SBF;           // NLOCAL*9
    float* btot   = amlp   + (size_t)NLOCAL*SBF;          // 3*2*128
    int*   tcnt   = (int*)(btot + 3*2*128);               // 1 (+3 pad)
    int*   c_ij   = tcnt + 4;                             // NTRIPLE
    int*   c_ka   = c_ij + NTRIPLE;                       // NTRIPLE
    float* c_cf   = (float*)(c_ka + NTRIPLE);             // 9*NTRIPLE (AoS)
    ushort* edgeEh = (ushort*)(c_cf + (size_t)9*NTRIPLE); // NEDGE*128 bf16
    ushort* embedAh = edgeEh + (size_t)NEDGE*UNITS;       // NTOTAL*128 bf16 (L0 gathers)
    ushort* aggAh   = embedAh + (size_t)NTOTAL*UNITS;     // NLOCAL*128 bf16 (L>=1 gathers)
    ushort* wmain  = aggAh + (size_t)NLOCAL*UNITS;        // 3*4*49152
    ushort* wext   = wmain + (size_t)3*4*49152;           // 3*2*4096
    ushort* waux   = wext  + (size_t)3*2*4096;            // 3*3*4096

    float* out = (float*)d_out;
    hipMemsetAsync(out, 0, sizeof(float), stream);
    hipMemsetAsync(tcnt, 0, sizeof(int), stream);

    k_pack_w   <<<(3*4*12*8*64 + 255)/256, 256, 0, stream>>>(gewm, gewg, gawm, gawg, wmain);
    k_pack_ext <<<(3*2*512 + 255)/256, 256, 0, stream>>>(gewm, gewg, tbgw, wext);
    k_pack_aux <<<(3*3*512 + 255)/256, 256, 0, stream>>>(elew, elaw, tbgw, waux);
    k_pack_bias<<<(3*2*128 + 255)/256, 256, 0, stream>>>(gewm, gewg, gebm, gebg, tbgb, btot);
    k_edge_geom<<<(NEDGE+255)/256, 256, 0, stream>>>(pos, cell, pbc, esrc, edst, batch,
                                                     evec, elen, rbf0);
    k_embed<<<(NTOTAL*32+255)/256, 256, 0, stream>>>(anum, embw, embedF, embedAh);
    k_edge_enc<<<(NEDGE*32+255)/256, 256, 0, stream>>>(rbf0, encw, encb, edgeEh);
    k_triple_compact<<<(NTRIPLE+255)/256, 256, 0, stream>>>(evec, elen, esrc, tbi,
                                                            tcnt, c_ij, c_ka, c_cf);

    const int gemm_blocks = (NEDGE + MEDGE - 1)/MEDGE;
    float*  Fin[3]  = { embedF, aggA, aggB };
    float*  Aout[3] = { aggA,   aggB, aggA };
    for (int L = 0; L < NLAYERS; L++){
        const ushort* wmL = wmain + (size_t)L*4*49152;
        const ushort* wxL = wext  + (size_t)L*2*4096;
        const ushort* waL = waux  + (size_t)L*3*4096;
        k_tb_mlp<<<(NLOCAL+255)/256, 256, 0, stream>>>(Fin[L],
            tbaw + (size_t)L*UNITS*SBF, tbab + (size_t)L*SBF, amlp, Aout[L], aggAh);
        hipMemsetAsync(tbout, 0, (size_t)NEDGE*SBF*sizeof(float), stream);
        k_triple_apply<<<512, 256, 0, stream>>>(tcnt, c_ij, c_ka, c_cf, amlp, tbout);
        const ushort* AhL = (L == 0) ? embedAh : aggAh;
        k_gated_fused<<<gemm_blocks, 512, 0, stream>>>(AhL, (L > 0) ? 1 : 0, gmap,
            edgeEh, (L < NLAYERS-1) ? 1 : 0,
            esrc, edst, rbf0, tbout,
            wmL + 0*49152, wmL + 1*49152, wmL + 2*49152, wmL + 3*49152,
            wxL + 0*4096,  wxL + 1*4096,
            waL + 0*4096,  waL + 1*4096, waL + 2*4096,
            btot + (size_t)L*2*128, btot + (size_t)L*2*128 + 128,
            gabm + (size_t)L*UNITS, gabg + (size_t)L*UNITS,
            tbgb + (size_t)L*UNITS, eleb + (size_t)L*UNITS, elab + (size_t)L*UNITS,
            Aout[L]);
    }
    k_final<<<1024, 256, 0, stream>>>(aggA, fw1, fb1, fw2, fb2, anum, escl, eshf, out);
}